// Round 1
// baseline (383.177 us; speedup 1.0000x reference)
//
#include <hip/hip_runtime.h>
#include <math.h>

#define BT 256      // B*T groups
#define RR 512      // rods per group
#define DD 256      // D
#define DH 128      // D/2
#define CHUNK 32
#define NTHREADS 512
#define HALVES 2    // blockIdx.y splits the 16 chunks

__device__ __forceinline__ float fast_gelu(float x) {
    // jax.nn.gelu approximate=True (tanh form)
    float u = 0.7978845608028654f * (x + 0.044715f * x * x * x);
    float au = fabsf(u);
    float e = __expf(-2.0f * au);
    float th = (1.0f - e) * __builtin_amdgcn_rcpf(1.0f + e);
    th = copysignf(th, u);
    return 0.5f * x * (1.0f + th);
}

__global__ __launch_bounds__(NTHREADS, 4)
void eq_head_kernel(const float* __restrict__ SF,   // (BT, 256)
                    const float* __restrict__ Q,    // (BT, 512, 4)
                    const float* __restrict__ TR,   // (BT, 512, 3)
                    const float* __restrict__ W1,   // (259, 256)
                    const float* __restrict__ b1,   // (256)
                    const float* __restrict__ W2,   // (256, 128)
                    const float* __restrict__ b2,   // (128)
                    const float* __restrict__ Wt,   // (128, 3)
                    const float* __restrict__ bt,   // (3)
                    const float* __restrict__ Wr,   // (128, 3)
                    const float* __restrict__ br,   // (3)
                    float* __restrict__ out)        // (BT, 512, 7)
{
    __shared__ float sS[DD];            // scalar features row
    __shared__ float sW1t[3][DD];       // W1 tail rows 256..258
    __shared__ float sBase[DD];         // s @ W1[:256] + b1
    __shared__ float sWt[DH * 3];
    __shared__ float sWr[DH * 3];
    __shared__ float sB2[DH];
    __shared__ float sCent[3];
    __shared__ float sLrp[CHUNK][3];
    __shared__ float sQn[CHUNK][4];
    __shared__ float sQraw[CHUNK][4];
    __shared__ float sDot[CHUNK][6];
    __shared__ float sH1[CHUNK][DD];    // 32 KB (also init-phase scratch)
    __shared__ float sH2[CHUNK][DH];    // 16 KB

    const int g = blockIdx.x;
    const int t = threadIdx.x;
    float* scratch = &sH1[0][0];        // 8192 floats of scratch during init

    // ---------------- stage small tensors ----------------
    if (t < DD) sS[t] = SF[g * DD + t];
    for (int idx = t; idx < 3 * DD; idx += NTHREADS)
        ((float*)sW1t)[idx] = W1[DD * DD + idx];       // rows 256..258 flat
    if (t < DH * 3) { sWt[t] = Wt[t]; sWr[t] = Wr[t]; }
    if (t < DH) sB2[t] = b2[t];

    // ---------------- centroid over all 512 rods ----------------
    {
        const float* trp = TR + ((size_t)g * RR + t) * 3;
        scratch[t]        = trp[0];
        scratch[512 + t]  = trp[1];
        scratch[1024 + t] = trp[2];
    }
    __syncthreads();
    for (int s = 256; s > 0; s >>= 1) {
        if (t < s) {
            scratch[t]        += scratch[t + s];
            scratch[512 + t]  += scratch[512 + t + s];
            scratch[1024 + t] += scratch[1024 + t + s];
        }
        __syncthreads();
    }
    if (t < 3) sCent[t] = scratch[t * 512] * (1.0f / RR);
    __syncthreads();

    // ---------------- base = s @ W1[:256] + b1 ----------------
    {
        const int j = t & 255;
        const int half = t >> 8;
        float acc0 = 0.0f;
        const int k0 = half * 128;
        for (int k = k0; k < k0 + 128; ++k)
            acc0 += sS[k] * W1[k * DD + j];
        scratch[t] = acc0;               // scratch free again (post-sync above)
        __syncthreads();
        if (t < DD) sBase[t] = scratch[t] + scratch[DD + t] + b1[t];
        __syncthreads();
    }

    // ---------------- main loop over row chunks ----------------
    const float4* Qv = (const float4*)Q + (size_t)g * RR;
    const int rp = t >> 5;            // 0..15 row pair
    const int c0 = (t & 31) * 4;      // output col base

    const int cfirst = blockIdx.y * (RR / CHUNK / HALVES);   // 8 chunks per block
    for (int cc = 0; cc < RR / CHUNK / HALVES; ++cc) {
        const int r0 = (cfirst + cc) * CHUNK;

        // phase 1: per-row quaternion prep (rod-local frame)
        if (t < CHUNK) {
            float4 q = Qv[r0 + t];
            const float* trp = TR + ((size_t)g * RR + r0 + t) * 3;
            float rx = trp[0] - sCent[0];
            float ry = trp[1] - sCent[1];
            float rz = trp[2] - sCent[2];
            float qw = q.x, qx = q.y, qy = q.z, qz = q.w;
            float n = sqrtf(qw * qw + qx * qx + qy * qy + qz * qz) + 1e-8f;
            float inv = 1.0f / n;
            float nw = qw * inv, nx = qx * inv, ny = qy * inv, nz = qz * inv;
            sQraw[t][0] = qw; sQraw[t][1] = qx; sQraw[t][2] = qy; sQraw[t][3] = qz;
            sQn[t][0] = nw; sQn[t][1] = nx; sQn[t][2] = ny; sQn[t][3] = nz;
            float xx = nx * nx, yy = ny * ny, zz = nz * nz;
            float xy = nx * ny, xz = nx * nz, yz = ny * nz;
            float wx = nw * nx, wy = nw * ny, wz = nw * nz;
            float m00 = 1.f - 2.f * (yy + zz), m01 = 2.f * (xy - wz), m02 = 2.f * (xz + wy);
            float m10 = 2.f * (xy + wz), m11 = 1.f - 2.f * (xx + zz), m12 = 2.f * (yz - wx);
            float m20 = 2.f * (xz - wy), m21 = 2.f * (yz + wx), m22 = 1.f - 2.f * (xx + yy);
            // conjugate rotation = M^T @ rel
            sLrp[t][0] = m00 * rx + m10 * ry + m20 * rz;
            sLrp[t][1] = m01 * rx + m11 * ry + m21 * rz;
            sLrp[t][2] = m02 * rx + m12 * ry + m22 * rz;
        }
        __syncthreads();

        // phase 2: h1 = gelu(base + lrp . W1tail), 32x256 elements
        #pragma unroll
        for (int i = 0; i < (CHUNK * DD) / NTHREADS; ++i) {
            int idx = i * NTHREADS + t;
            int row = idx >> 8, col = idx & 255;
            float v = sBase[col]
                    + sLrp[row][0] * sW1t[0][col]
                    + sLrp[row][1] * sW1t[1][col]
                    + sLrp[row][2] * sW1t[2][col];
            sH1[row][col] = fast_gelu(v);
        }
        __syncthreads();

        // phase 3: GEMM h1(32x256) @ W2(256x128) -> h2, 2 rows x 4 cols / thread
        {
            float acc[8];
            #pragma unroll
            for (int i = 0; i < 8; ++i) acc[i] = 0.0f;
            const float* w2p = W2 + c0;
            const float* h1a = sH1[2 * rp];
            const float* h1b = sH1[2 * rp + 1];
            #pragma unroll 4
            for (int k = 0; k < DD; ++k) {
                float4 w = *(const float4*)(w2p + k * DH);
                float a = h1a[k], b = h1b[k];
                acc[0] += a * w.x; acc[1] += a * w.y;
                acc[2] += a * w.z; acc[3] += a * w.w;
                acc[4] += b * w.x; acc[5] += b * w.y;
                acc[6] += b * w.z; acc[7] += b * w.w;
            }
            float4 oA, oB;
            oA.x = fast_gelu(acc[0] + sB2[c0 + 0]);
            oA.y = fast_gelu(acc[1] + sB2[c0 + 1]);
            oA.z = fast_gelu(acc[2] + sB2[c0 + 2]);
            oA.w = fast_gelu(acc[3] + sB2[c0 + 3]);
            oB.x = fast_gelu(acc[4] + sB2[c0 + 0]);
            oB.y = fast_gelu(acc[5] + sB2[c0 + 1]);
            oB.z = fast_gelu(acc[6] + sB2[c0 + 2]);
            oB.w = fast_gelu(acc[7] + sB2[c0 + 3]);
            *(float4*)&sH2[2 * rp][c0] = oA;
            *(float4*)&sH2[2 * rp + 1][c0] = oB;
        }
        __syncthreads();

        // phase 4: head dots — 32 rows x 6 outputs, 2 threads per dot
        if (t < 384) {
            int o = t >> 1;
            int row = o / 6;
            int j = o - row * 6;
            int half = t & 1;
            const float* wcol = (j < 3) ? (sWt + j) : (sWr + (j - 3));
            const float* h2r = sH2[row];
            float a = 0.0f;
            #pragma unroll 4
            for (int kk = 0; kk < 64; ++kk) {
                int k = half * 64 + kk;
                a += h2r[k] * wcol[k * 3];
            }
            a += __shfl_xor(a, 1);
            if (half == 0) sDot[row][j] = a;
        }
        __syncthreads();

        // phase 5: per-row epilogue (rotate trans_vel, quaternion velocity)
        if (t < CHUNK) {
            float qw = sQraw[t][0], qx = sQraw[t][1], qy = sQraw[t][2], qz = sQraw[t][3];
            float nw = sQn[t][0], nx = sQn[t][1], ny = sQn[t][2], nz = sQn[t][3];
            float tvp0 = sDot[t][0] + bt[0];
            float tvp1 = sDot[t][1] + bt[1];
            float tvp2 = sDot[t][2] + bt[2];
            float rv0 = (sDot[t][3] + br[0]) * 0.1f;
            float rv1 = (sDot[t][4] + br[1]) * 0.1f;
            float rv2 = (sDot[t][5] + br[2]) * 0.1f;
            float xx = nx * nx, yy = ny * ny, zz = nz * nz;
            float xy = nx * ny, xz = nx * nz, yz = ny * nz;
            float wx = nw * nx, wy = nw * ny, wz = nw * nz;
            float m00 = 1.f - 2.f * (yy + zz), m01 = 2.f * (xy - wz), m02 = 2.f * (xz + wy);
            float m10 = 2.f * (xy + wz), m11 = 1.f - 2.f * (xx + zz), m12 = 2.f * (yz - wx);
            float m20 = 2.f * (xz - wy), m21 = 2.f * (yz + wx), m22 = 1.f - 2.f * (xx + yy);
            float tv0 = m00 * tvp0 + m01 * tvp1 + m02 * tvp2;
            float tv1 = m10 * tvp0 + m11 * tvp1 + m12 * tvp2;
            float tv2 = m20 * tvp0 + m21 * tvp1 + m22 * tvp2;
            float* op = out + ((size_t)g * RR + r0 + t) * 7;
            op[0] = -0.5f * (qx * rv0 + qy * rv1 + qz * rv2);
            op[1] =  0.5f * (qw * rv0 + qy * rv2 - qz * rv1);
            op[2] =  0.5f * (qw * rv1 - qx * rv2 + qz * rv0);
            op[3] =  0.5f * (qw * rv2 + qx * rv1 - qy * rv0);
            op[4] = tv0; op[5] = tv1; op[6] = tv2;
        }
        __syncthreads();
    }
}

extern "C" void kernel_launch(void* const* d_in, const int* in_sizes, int n_in,
                              void* d_out, int out_size, void* d_ws, size_t ws_size,
                              hipStream_t stream) {
    const float* SF = (const float*)d_in[0];
    const float* Q  = (const float*)d_in[1];
    const float* TR = (const float*)d_in[2];
    const float* W1 = (const float*)d_in[3];
    const float* b1 = (const float*)d_in[4];
    const float* W2 = (const float*)d_in[5];
    const float* b2 = (const float*)d_in[6];
    const float* Wt = (const float*)d_in[7];
    const float* bt = (const float*)d_in[8];
    const float* Wr = (const float*)d_in[9];
    const float* br = (const float*)d_in[10];
    float* out = (float*)d_out;

    dim3 grid(BT, HALVES);
    eq_head_kernel<<<grid, NTHREADS, 0, stream>>>(SF, Q, TR, W1, b1, W2, b2,
                                                  Wt, bt, Wr, br, out);
}

// Round 2
// 156.874 us; speedup vs baseline: 2.4426x; 2.4426x over previous
//
#include <hip/hip_runtime.h>
#include <math.h>

#define BT 256      // B*T groups
#define RR 512      // rods per group
#define DD 256      // D
#define DH 128      // D/2
#define CHUNK 64
#define NTHREADS 512
#define HALVES 2
#define STRH1 264   // bf16 elems per h1 row (256 + 8 pad) -> 132 dw, ≡4 mod 32
#define STRH2 132   // f32 elems per h2 row (128 + 4 pad)  -> ≡4 mod 32

typedef __bf16 bf16x8 __attribute__((ext_vector_type(8)));
typedef unsigned short u16x8 __attribute__((ext_vector_type(8)));
typedef float f32x4 __attribute__((ext_vector_type(4)));

__device__ __forceinline__ float fast_gelu(float x) {
    float u = 0.7978845608028654f * (x + 0.044715f * x * x * x);
    float au = fabsf(u);
    float e = __expf(-2.0f * au);
    float th = (1.0f - e) * __builtin_amdgcn_rcpf(1.0f + e);
    th = copysignf(th, u);
    return 0.5f * x * (1.0f + th);
}

__device__ __forceinline__ unsigned short bf_bits(float x) {
    union { float f; unsigned u; } c; c.f = x;
    unsigned r = c.u + 0x7FFFu + ((c.u >> 16) & 1u);   // RTNE
    return (unsigned short)(r >> 16);
}

__global__ __launch_bounds__(NTHREADS, 4)
void eq_head_kernel(const float* __restrict__ SF,   // (BT, 256)
                    const float* __restrict__ Q,    // (BT, 512, 4)
                    const float* __restrict__ TR,   // (BT, 512, 3)
                    const float* __restrict__ W1,   // (259, 256)
                    const float* __restrict__ b1,   // (256)
                    const float* __restrict__ W2,   // (256, 128)
                    const float* __restrict__ b2,   // (128)
                    const float* __restrict__ Wt,   // (128, 3)
                    const float* __restrict__ bt,   // (3)
                    const float* __restrict__ Wr,   // (128, 3)
                    const float* __restrict__ br,   // (3)
                    float* __restrict__ out)        // (BT, 512, 7)
{
    // Aliased big buffer: h1 (bf16 64x264 = 33792 B)  <->  h2 (f32 64x132 = 33792 B)
    __shared__ char sBuf[CHUNK * STRH1 * 2];
    __shared__ float sLrp[RR][3];       // local_rel_pos for ALL rods (6 KB)
    __shared__ float sS[DD];
    __shared__ float sW1t[3][DD];
    __shared__ float sBase[DD];
    __shared__ float sWtL[DH * 3];
    __shared__ float sWrL[DH * 3];
    __shared__ float sB2[DH];
    __shared__ float sDot[CHUNK][6];
    __shared__ float sCent[3];
    __shared__ float sBt[3];
    __shared__ float sBr[3];

    unsigned short* sH1u = (unsigned short*)sBuf;
    float* sH2f = (float*)sBuf;
    float* scratch = (float*)sBuf;      // init-phase scratch (8448 floats avail)

    const int g = blockIdx.x;
    const int t = threadIdx.x;

    // ---------------- stage small tensors ----------------
    if (t < DD) sS[t] = SF[g * DD + t];
    for (int idx = t; idx < 3 * DD; idx += NTHREADS)
        ((float*)sW1t)[idx] = W1[DD * DD + idx];
    if (t < DH * 3) { sWtL[t] = Wt[t]; sWrL[t] = Wr[t]; }
    if (t < DH) sB2[t] = b2[t];
    if (t < 3) { sBt[t] = bt[t]; sBr[t] = br[t]; }

    // ---------------- centroid over 512 rods ----------------
    {
        const float* trp = TR + ((size_t)g * RR + t) * 3;
        scratch[t]        = trp[0];
        scratch[512 + t]  = trp[1];
        scratch[1024 + t] = trp[2];
    }
    __syncthreads();
    for (int s = 256; s > 0; s >>= 1) {
        if (t < s) {
            scratch[t]        += scratch[t + s];
            scratch[512 + t]  += scratch[512 + t + s];
            scratch[1024 + t] += scratch[1024 + t + s];
        }
        __syncthreads();
    }
    if (t < 3) sCent[t] = scratch[t * 512] * (1.0f / RR);
    __syncthreads();

    // ---------------- local_rel_pos for all 512 rods (one thread each) --------
    {
        const float4 q = ((const float4*)Q)[(size_t)g * RR + t];
        const float* trp = TR + ((size_t)g * RR + t) * 3;
        float rx = trp[0] - sCent[0];
        float ry = trp[1] - sCent[1];
        float rz = trp[2] - sCent[2];
        float qw = q.x, qx = q.y, qy = q.z, qz = q.w;
        float n = sqrtf(qw * qw + qx * qx + qy * qy + qz * qz) + 1e-8f;
        float inv = 1.0f / n;
        float nw = qw * inv, nx = qx * inv, ny = qy * inv, nz = qz * inv;
        float xx = nx * nx, yy = ny * ny, zz = nz * nz;
        float xy = nx * ny, xz = nx * nz, yz = ny * nz;
        float wx = nw * nx, wy = nw * ny, wz = nw * nz;
        float m00 = 1.f - 2.f * (yy + zz), m01 = 2.f * (xy - wz), m02 = 2.f * (xz + wy);
        float m10 = 2.f * (xy + wz), m11 = 1.f - 2.f * (xx + zz), m12 = 2.f * (yz - wx);
        float m20 = 2.f * (xz - wy), m21 = 2.f * (yz + wx), m22 = 1.f - 2.f * (xx + yy);
        // conjugate rotation = M^T @ rel
        sLrp[t][0] = m00 * rx + m10 * ry + m20 * rz;
        sLrp[t][1] = m01 * rx + m11 * ry + m21 * rz;
        sLrp[t][2] = m02 * rx + m12 * ry + m22 * rz;
    }

    // ---------------- base = s @ W1[:256] + b1 ----------------
    {
        const int j = t & 255;
        const int half = t >> 8;
        float acc0 = 0.0f;
        const int k0 = half * 128;
        for (int k = k0; k < k0 + 128; ++k)
            acc0 += sS[k] * W1[k * DD + j];
        __syncthreads();                 // centroid/scratch reads all done
        scratch[t] = acc0;
        __syncthreads();
        if (t < DD) sBase[t] = scratch[t] + scratch[DD + t] + b1[t];
    }

    // ---------------- W2 -> per-wave B fragments in registers ----------------
    const int wv = t >> 6;            // wave 0..7 owns n-tile wv
    const int ln = t & 15;            // lane&15
    const int lq = (t >> 4) & 3;      // quad
    const int colN = (wv << 4) + ln;  // output column this lane owns
    bf16x8 Breg[8];
    #pragma unroll
    for (int ks = 0; ks < 8; ++ks) {
        u16x8 tmp;
        #pragma unroll
        for (int i = 0; i < 8; ++i) {
            int k = ks * 32 + lq * 8 + i;
            tmp[i] = bf_bits(W2[k * DH + colN]);
        }
        Breg[ks] = __builtin_bit_cast(bf16x8, tmp);
    }
    __syncthreads();   // sBase, sLrp, staging all visible; scratch reads done

    // ---------------- main loop: 4 chunks of 64 rods ----------------
    const float4* Qv = (const float4*)Q + (size_t)g * RR;
    const int cfirst = blockIdx.y * (RR / CHUNK / HALVES);

    for (int cc = 0; cc < RR / CHUNK / HALVES; ++cc) {
        const int r0 = (cfirst + cc) * CHUNK;

        // phase 2: h1 = gelu(base + lrp.W1tail), bf16 into LDS (pairs)
        #pragma unroll
        for (int i = 0; i < (CHUNK * DD / 2) / NTHREADS; ++i) {   // 16 iters
            int p = i * NTHREADS + t;
            int row = p >> 7;                 // 128 col-pairs per row
            int cp = (p & 127) * 2;
            float l0 = sLrp[r0 + row][0];
            float l1 = sLrp[r0 + row][1];
            float l2 = sLrp[r0 + row][2];
            float v0 = sBase[cp]     + l0 * sW1t[0][cp]     + l1 * sW1t[1][cp]     + l2 * sW1t[2][cp];
            float v1 = sBase[cp + 1] + l0 * sW1t[0][cp + 1] + l1 * sW1t[1][cp + 1] + l2 * sW1t[2][cp + 1];
            unsigned pack = (unsigned)bf_bits(fast_gelu(v0))
                          | ((unsigned)bf_bits(fast_gelu(v1)) << 16);
            *(unsigned*)&sH1u[row * STRH1 + cp] = pack;
        }
        __syncthreads();

        // phase 3: MFMA  h1(64x256) @ W2(256x128);  wave wv -> cols [16wv,16wv+16)
        f32x4 acc0 = {0.f, 0.f, 0.f, 0.f};
        f32x4 acc1 = {0.f, 0.f, 0.f, 0.f};
        f32x4 acc2 = {0.f, 0.f, 0.f, 0.f};
        f32x4 acc3 = {0.f, 0.f, 0.f, 0.f};
        {
            const unsigned short* aBase = sH1u + ln * STRH1 + lq * 8;
            #pragma unroll
            for (int ks = 0; ks < 8; ++ks) {
                bf16x8 b = Breg[ks];
                bf16x8 a0 = *(const bf16x8*)(aBase + ks * 32);
                bf16x8 a1 = *(const bf16x8*)(aBase + 16 * STRH1 + ks * 32);
                bf16x8 a2 = *(const bf16x8*)(aBase + 32 * STRH1 + ks * 32);
                bf16x8 a3 = *(const bf16x8*)(aBase + 48 * STRH1 + ks * 32);
                acc0 = __builtin_amdgcn_mfma_f32_16x16x32_bf16(a0, b, acc0, 0, 0, 0);
                acc1 = __builtin_amdgcn_mfma_f32_16x16x32_bf16(a1, b, acc1, 0, 0, 0);
                acc2 = __builtin_amdgcn_mfma_f32_16x16x32_bf16(a2, b, acc2, 0, 0, 0);
                acc3 = __builtin_amdgcn_mfma_f32_16x16x32_bf16(a3, b, acc3, 0, 0, 0);
            }
        }
        __syncthreads();    // all h1 reads complete before aliased h2 writes

        // h2 = gelu(D + b2) -> f32 LDS (stride 132, conflict-free)
        {
            float bb = sB2[colN];
            #pragma unroll
            for (int r = 0; r < 4; ++r) {
                int rowq = lq * 4 + r;
                sH2f[(rowq)      * STRH2 + colN] = fast_gelu(acc0[r] + bb);
                sH2f[(rowq + 16) * STRH2 + colN] = fast_gelu(acc1[r] + bb);
                sH2f[(rowq + 32) * STRH2 + colN] = fast_gelu(acc2[r] + bb);
                sH2f[(rowq + 48) * STRH2 + colN] = fast_gelu(acc3[r] + bb);
            }
        }
        __syncthreads();

        // phase 4: head dots — 64 rows x 6 outputs, one thread per dot
        if (t < CHUNK * 6) {
            int row = t / 6;
            int j = t - row * 6;
            const float* h2r = sH2f + row * STRH2;
            const float* wc = (j < 3) ? (sWtL + j) : (sWrL + (j - 3));
            float a = 0.0f;
            #pragma unroll 8
            for (int k = 0; k < DH; ++k)
                a += h2r[k] * wc[k * 3];
            sDot[row][j] = a;
        }
        __syncthreads();

        // phase 5: per-row epilogue
        if (t < CHUNK) {
            float4 q = Qv[r0 + t];
            float qw = q.x, qx = q.y, qy = q.z, qz = q.w;
            float n = sqrtf(qw * qw + qx * qx + qy * qy + qz * qz) + 1e-8f;
            float inv = 1.0f / n;
            float nw = qw * inv, nx = qx * inv, ny = qy * inv, nz = qz * inv;
            float tvp0 = sDot[t][0] + sBt[0];
            float tvp1 = sDot[t][1] + sBt[1];
            float tvp2 = sDot[t][2] + sBt[2];
            float rv0 = (sDot[t][3] + sBr[0]) * 0.1f;
            float rv1 = (sDot[t][4] + sBr[1]) * 0.1f;
            float rv2 = (sDot[t][5] + sBr[2]) * 0.1f;
            float xx = nx * nx, yy = ny * ny, zz = nz * nz;
            float xy = nx * ny, xz = nx * nz, yz = ny * nz;
            float wx = nw * nx, wy = nw * ny, wz = nw * nz;
            float m00 = 1.f - 2.f * (yy + zz), m01 = 2.f * (xy - wz), m02 = 2.f * (xz + wy);
            float m10 = 2.f * (xy + wz), m11 = 1.f - 2.f * (xx + zz), m12 = 2.f * (yz - wx);
            float m20 = 2.f * (xz - wy), m21 = 2.f * (yz + wx), m22 = 1.f - 2.f * (xx + yy);
            float tv0 = m00 * tvp0 + m01 * tvp1 + m02 * tvp2;
            float tv1 = m10 * tvp0 + m11 * tvp1 + m12 * tvp2;
            float tv2 = m20 * tvp0 + m21 * tvp1 + m22 * tvp2;
            float* op = out + ((size_t)g * RR + r0 + t) * 7;
            op[0] = -0.5f * (qx * rv0 + qy * rv1 + qz * rv2);
            op[1] =  0.5f * (qw * rv0 + qy * rv2 - qz * rv1);
            op[2] =  0.5f * (qw * rv1 - qx * rv2 + qz * rv0);
            op[3] =  0.5f * (qw * rv2 + qx * rv1 - qy * rv0);
            op[4] = tv0; op[5] = tv1; op[6] = tv2;
        }
        __syncthreads();
    }
}

extern "C" void kernel_launch(void* const* d_in, const int* in_sizes, int n_in,
                              void* d_out, int out_size, void* d_ws, size_t ws_size,
                              hipStream_t stream) {
    const float* SF = (const float*)d_in[0];
    const float* Q  = (const float*)d_in[1];
    const float* TR = (const float*)d_in[2];
    const float* W1 = (const float*)d_in[3];
    const float* b1 = (const float*)d_in[4];
    const float* W2 = (const float*)d_in[5];
    const float* b2 = (const float*)d_in[6];
    const float* Wt = (const float*)d_in[7];
    const float* bt = (const float*)d_in[8];
    const float* Wr = (const float*)d_in[9];
    const float* br = (const float*)d_in[10];
    float* out = (float*)d_out;

    dim3 grid(BT, HALVES);
    eq_head_kernel<<<grid, NTHREADS, 0, stream>>>(SF, Q, TR, W1, b1, W2, b2,
                                                  Wt, bt, Wr, br, out);
}

// Round 3
// 145.776 us; speedup vs baseline: 2.6285x; 1.0761x over previous
//
#include <hip/hip_runtime.h>
#include <math.h>

#define BT 256      // B*T groups
#define RR 512      // rods per group
#define DD 256      // D
#define DH 128      // D/2
#define CHUNK 64
#define NTHREADS 512
#define HALVES 2
#define STRH1 264   // bf16 elems per h1 row (256 + 8 pad)
#define STRH2B 136  // bf16 elems per h2 row (128 + 8 pad)

typedef __bf16 bf16x8 __attribute__((ext_vector_type(8)));
typedef unsigned short u16x8 __attribute__((ext_vector_type(8)));
typedef float f32x4 __attribute__((ext_vector_type(4)));

__device__ __forceinline__ float fast_gelu(float x) {
    float u = 0.7978845608028654f * (x + 0.044715f * x * x * x);
    float au = fabsf(u);
    float e = __expf(-2.0f * au);
    float th = (1.0f - e) * __builtin_amdgcn_rcpf(1.0f + e);
    th = copysignf(th, u);
    return 0.5f * x * (1.0f + th);
}

__device__ __forceinline__ unsigned short bf_bits(float x) {
    union { float f; unsigned u; } c; c.f = x;
    unsigned r = c.u + 0x7FFFu + ((c.u >> 16) & 1u);   // RTNE
    return (unsigned short)(r >> 16);
}

__global__ __launch_bounds__(NTHREADS, 4)
void eq_head_kernel(const float* __restrict__ SF,   // (BT, 256)
                    const float* __restrict__ Q,    // (BT, 512, 4)
                    const float* __restrict__ TR,   // (BT, 512, 3)
                    const float* __restrict__ W1,   // (259, 256)
                    const float* __restrict__ b1,   // (256)
                    const float* __restrict__ W2,   // (256, 128)
                    const float* __restrict__ b2,   // (128)
                    const float* __restrict__ Wt,   // (128, 3)
                    const float* __restrict__ bt,   // (3)
                    const float* __restrict__ Wr,   // (128, 3)
                    const float* __restrict__ br,   // (3)
                    float* __restrict__ out)        // (BT, 512, 7)
{
    // big aliased buffer: h1 bf16 [64][264] (33792 B) <-> h2 bf16 [64][136] <-> init scratch
    __shared__ char sBuf[CHUNK * STRH1 * 2];
    __shared__ float sLrp[RR][3];
    __shared__ float sS[DD];
    __shared__ float sW1t[3][DD];
    __shared__ float sBase[DD];
    __shared__ float sB2[DH];
    __shared__ unsigned short sWB[4 * 512];   // head-B fragments, 4 K-steps
    __shared__ float sDot[CHUNK][6];
    __shared__ float sCent[3];
    __shared__ float sBt[3];
    __shared__ float sBr[3];

    unsigned short* sH1u = (unsigned short*)sBuf;
    unsigned short* sH2b = (unsigned short*)sBuf;
    float* scratch = (float*)sBuf;

    const int g = blockIdx.x;
    const int t = threadIdx.x;
    const int wv = t >> 6;            // wave 0..7
    const int wl = t & 63;            // lane in wave
    const int ln = t & 15;            // lane & 15
    const int lq = (t >> 4) & 3;      // quad in wave
    const int colN = (wv << 4) + ln;  // W2 output column owned in phase 3

    // ---------------- stage small tensors ----------------
    if (t < DD) sS[t] = SF[g * DD + t];
    for (int idx = t; idx < 3 * DD; idx += NTHREADS)
        ((float*)sW1t)[idx] = W1[DD * DD + idx];
    if (t < DH) sB2[t] = b2[t];
    if (t < 3) { sBt[t] = bt[t]; sBr[t] = br[t]; }

    // head-B fragments: [Wt | Wr | 0-pad] (K=128, N=16) in 16x16x32 B layout
    for (int idx = t; idx < 2048; idx += NTHREADS) {
        int ks = idx >> 9;
        int rem = idx & 511;
        int lane = rem >> 3;
        int i = rem & 7;
        int bq = (lane >> 4) & 3;
        int bn = lane & 15;
        int k = ks * 32 + bq * 8 + i;
        float v = (bn < 3) ? Wt[k * 3 + bn] : (bn < 6 ? Wr[k * 3 + bn - 3] : 0.0f);
        sWB[idx] = bf_bits(v);
    }

    // ---------------- centroid over 512 rods ----------------
    {
        const float* trp = TR + ((size_t)g * RR + t) * 3;
        scratch[t]        = trp[0];
        scratch[512 + t]  = trp[1];
        scratch[1024 + t] = trp[2];
    }
    __syncthreads();
    for (int s = 256; s > 0; s >>= 1) {
        if (t < s) {
            scratch[t]        += scratch[t + s];
            scratch[512 + t]  += scratch[512 + t + s];
            scratch[1024 + t] += scratch[1024 + t + s];
        }
        __syncthreads();
    }
    if (t < 3) sCent[t] = scratch[t * 512] * (1.0f / RR);
    __syncthreads();

    // ---------------- local_rel_pos for all 512 rods ----------------
    {
        const float4 q = ((const float4*)Q)[(size_t)g * RR + t];
        const float* trp = TR + ((size_t)g * RR + t) * 3;
        float rx = trp[0] - sCent[0];
        float ry = trp[1] - sCent[1];
        float rz = trp[2] - sCent[2];
        float qw = q.x, qx = q.y, qy = q.z, qz = q.w;
        float n = sqrtf(qw * qw + qx * qx + qy * qy + qz * qz) + 1e-8f;
        float inv = 1.0f / n;
        float nw = qw * inv, nx = qx * inv, ny = qy * inv, nz = qz * inv;
        float xx = nx * nx, yy = ny * ny, zz = nz * nz;
        float xy = nx * ny, xz = nx * nz, yz = ny * nz;
        float wx = nw * nx, wy = nw * ny, wz = nw * nz;
        float m00 = 1.f - 2.f * (yy + zz), m01 = 2.f * (xy - wz), m02 = 2.f * (xz + wy);
        float m10 = 2.f * (xy + wz), m11 = 1.f - 2.f * (xx + zz), m12 = 2.f * (yz - wx);
        float m20 = 2.f * (xz - wy), m21 = 2.f * (yz + wx), m22 = 1.f - 2.f * (xx + yy);
        sLrp[t][0] = m00 * rx + m10 * ry + m20 * rz;
        sLrp[t][1] = m01 * rx + m11 * ry + m21 * rz;
        sLrp[t][2] = m02 * rx + m12 * ry + m22 * rz;
    }

    // ---------------- base = s @ W1[:256] + b1 ----------------
    {
        const int j = t & 255;
        const int half = t >> 8;
        float acc0 = 0.0f;
        const int k0 = half * 128;
        for (int k = k0; k < k0 + 128; ++k)
            acc0 += sS[k] * W1[k * DD + j];
        __syncthreads();
        scratch[t] = acc0;
        __syncthreads();
        if (t < DD) sBase[t] = scratch[t] + scratch[DD + t] + b1[t];
    }

    // ---------------- W2 -> per-wave B fragments in registers ----------------
    bf16x8 Breg[8];
    #pragma unroll
    for (int ks = 0; ks < 8; ++ks) {
        u16x8 tmp;
        #pragma unroll
        for (int i = 0; i < 8; ++i) {
            int k = ks * 32 + lq * 8 + i;
            tmp[i] = bf_bits(W2[k * DH + colN]);
        }
        Breg[ks] = __builtin_bit_cast(bf16x8, tmp);
    }
    __syncthreads();   // sBase/sLrp/sWB visible; scratch free

    // phase-2 per-lane column cache: 4 consecutive cols per lane
    const int l4 = wl * 4;
    float4 base4 = *(const float4*)&sBase[l4];
    float4 w1ta  = *(const float4*)&sW1t[0][l4];
    float4 w1tb  = *(const float4*)&sW1t[1][l4];
    float4 w1tc  = *(const float4*)&sW1t[2][l4];

    // ---------------- main loop: 4 chunks of 64 rods ----------------
    const float4* Qv = (const float4*)Q + (size_t)g * RR;
    const int cfirst = blockIdx.y * (RR / CHUNK / HALVES);

    for (int cc = 0; cc < RR / CHUNK / HALVES; ++cc) {
        const int r0 = (cfirst + cc) * CHUNK;

        // phase 2: h1 = gelu(base + lrp.W1tail); wave wv owns rows wv*8..wv*8+7
        #pragma unroll
        for (int it = 0; it < 8; ++it) {
            int row = wv * 8 + it;
            float l0 = sLrp[r0 + row][0];    // broadcast reads
            float l1 = sLrp[r0 + row][1];
            float l2 = sLrp[r0 + row][2];
            float v0 = base4.x + l0 * w1ta.x + l1 * w1tb.x + l2 * w1tc.x;
            float v1 = base4.y + l0 * w1ta.y + l1 * w1tb.y + l2 * w1tc.y;
            float v2 = base4.z + l0 * w1ta.z + l1 * w1tb.z + l2 * w1tc.z;
            float v3 = base4.w + l0 * w1ta.w + l1 * w1tb.w + l2 * w1tc.w;
            unsigned p0 = (unsigned)bf_bits(fast_gelu(v0)) | ((unsigned)bf_bits(fast_gelu(v1)) << 16);
            unsigned p1 = (unsigned)bf_bits(fast_gelu(v2)) | ((unsigned)bf_bits(fast_gelu(v3)) << 16);
            uint2 pk; pk.x = p0; pk.y = p1;
            *(uint2*)&sH1u[row * STRH1 + l4] = pk;   // b64 write
        }
        __syncthreads();

        // phase 3: MFMA h1(64x256) @ W2(256x128); wave wv -> cols [16wv,16wv+16)
        f32x4 acc0 = {0.f, 0.f, 0.f, 0.f};
        f32x4 acc1 = {0.f, 0.f, 0.f, 0.f};
        f32x4 acc2 = {0.f, 0.f, 0.f, 0.f};
        f32x4 acc3 = {0.f, 0.f, 0.f, 0.f};
        {
            const unsigned short* aBase = sH1u + ln * STRH1 + lq * 8;
            #pragma unroll
            for (int ks = 0; ks < 8; ++ks) {
                bf16x8 b = Breg[ks];
                bf16x8 a0 = *(const bf16x8*)(aBase + ks * 32);
                bf16x8 a1 = *(const bf16x8*)(aBase + 16 * STRH1 + ks * 32);
                bf16x8 a2 = *(const bf16x8*)(aBase + 32 * STRH1 + ks * 32);
                bf16x8 a3 = *(const bf16x8*)(aBase + 48 * STRH1 + ks * 32);
                acc0 = __builtin_amdgcn_mfma_f32_16x16x32_bf16(a0, b, acc0, 0, 0, 0);
                acc1 = __builtin_amdgcn_mfma_f32_16x16x32_bf16(a1, b, acc1, 0, 0, 0);
                acc2 = __builtin_amdgcn_mfma_f32_16x16x32_bf16(a2, b, acc2, 0, 0, 0);
                acc3 = __builtin_amdgcn_mfma_f32_16x16x32_bf16(a3, b, acc3, 0, 0, 0);
            }
        }
        __syncthreads();    // all h1 reads done before aliased h2 writes

        // h2 = gelu(D + b2) -> bf16 LDS (aliased buffer)
        {
            float bb = sB2[colN];
            #pragma unroll
            for (int r = 0; r < 4; ++r) {
                int rq = lq * 4 + r;
                sH2b[(rq)      * STRH2B + colN] = bf_bits(fast_gelu(acc0[r] + bb));
                sH2b[(rq + 16) * STRH2B + colN] = bf_bits(fast_gelu(acc1[r] + bb));
                sH2b[(rq + 32) * STRH2B + colN] = bf_bits(fast_gelu(acc2[r] + bb));
                sH2b[(rq + 48) * STRH2B + colN] = bf_bits(fast_gelu(acc3[r] + bb));
            }
        }
        __syncthreads();

        // phase 4: head GEMM h2(64x128) @ W36(128x16) via MFMA, waves 0..3
        if (wv < 4) {
            f32x4 dacc = {0.f, 0.f, 0.f, 0.f};
            const unsigned short* aB = sH2b + (wv * 16 + ln) * STRH2B + lq * 8;
            #pragma unroll
            for (int ks = 0; ks < 4; ++ks) {
                bf16x8 a = *(const bf16x8*)(aB + ks * 32);
                bf16x8 b = *(const bf16x8*)(&sWB[ks * 512 + wl * 8]);
                dacc = __builtin_amdgcn_mfma_f32_16x16x32_bf16(a, b, dacc, 0, 0, 0);
            }
            if (ln < 6) {
                #pragma unroll
                for (int r = 0; r < 4; ++r)
                    sDot[wv * 16 + lq * 4 + r][ln] = dacc[r];
            }
        }
        __syncthreads();

        // phase 5: per-row epilogue
        if (t < CHUNK) {
            float4 q = Qv[r0 + t];
            float qw = q.x, qx = q.y, qy = q.z, qz = q.w;
            float n = sqrtf(qw * qw + qx * qx + qy * qy + qz * qz) + 1e-8f;
            float inv = 1.0f / n;
            float nw = qw * inv, nx = qx * inv, ny = qy * inv, nz = qz * inv;
            float tvp0 = sDot[t][0] + sBt[0];
            float tvp1 = sDot[t][1] + sBt[1];
            float tvp2 = sDot[t][2] + sBt[2];
            float rv0 = (sDot[t][3] + sBr[0]) * 0.1f;
            float rv1 = (sDot[t][4] + sBr[1]) * 0.1f;
            float rv2 = (sDot[t][5] + sBr[2]) * 0.1f;
            float xx = nx * nx, yy = ny * ny, zz = nz * nz;
            float xy = nx * ny, xz = nx * nz, yz = ny * nz;
            float wx = nw * nx, wy = nw * ny, wz = nw * nz;
            float m00 = 1.f - 2.f * (yy + zz), m01 = 2.f * (xy - wz), m02 = 2.f * (xz + wy);
            float m10 = 2.f * (xy + wz), m11 = 1.f - 2.f * (xx + zz), m12 = 2.f * (yz - wx);
            float m20 = 2.f * (xz - wy), m21 = 2.f * (yz + wx), m22 = 1.f - 2.f * (xx + yy);
            float tv0 = m00 * tvp0 + m01 * tvp1 + m02 * tvp2;
            float tv1 = m10 * tvp0 + m11 * tvp1 + m12 * tvp2;
            float tv2 = m20 * tvp0 + m21 * tvp1 + m22 * tvp2;
            float* op = out + ((size_t)g * RR + r0 + t) * 7;
            op[0] = -0.5f * (qx * rv0 + qy * rv1 + qz * rv2);
            op[1] =  0.5f * (qw * rv0 + qy * rv2 - qz * rv1);
            op[2] =  0.5f * (qw * rv1 - qx * rv2 + qz * rv0);
            op[3] =  0.5f * (qw * rv2 + qx * rv1 - qy * rv0);
            op[4] = tv0; op[5] = tv1; op[6] = tv2;
        }
        __syncthreads();
    }
}

extern "C" void kernel_launch(void* const* d_in, const int* in_sizes, int n_in,
                              void* d_out, int out_size, void* d_ws, size_t ws_size,
                              hipStream_t stream) {
    const float* SF = (const float*)d_in[0];
    const float* Q  = (const float*)d_in[1];
    const float* TR = (const float*)d_in[2];
    const float* W1 = (const float*)d_in[3];
    const float* b1 = (const float*)d_in[4];
    const float* W2 = (const float*)d_in[5];
    const float* b2 = (const float*)d_in[6];
    const float* Wt = (const float*)d_in[7];
    const float* bt = (const float*)d_in[8];
    const float* Wr = (const float*)d_in[9];
    const float* br = (const float*)d_in[10];
    float* out = (float*)d_out;

    dim3 grid(BT, HALVES);
    eq_head_kernel<<<grid, NTHREADS, 0, stream>>>(SF, Q, TR, W1, b1, W2, b2,
                                                  Wt, bt, Wr, br, out);
}

// Round 4
// 134.825 us; speedup vs baseline: 2.8420x; 1.0812x over previous
//
#include <hip/hip_runtime.h>
#include <math.h>

#define GB 256      // B*T groups
#define RR 512      // rods per group
#define DD 256      // D
#define DH 128      // D/2
#define NTHREADS 512

typedef __bf16 bf16x8 __attribute__((ext_vector_type(8)));
typedef unsigned short u16x8 __attribute__((ext_vector_type(8)));
typedef float f32x4 __attribute__((ext_vector_type(4)));

// ws layout (bytes)
#define OFF_LRP  0u            // 256*512*4 f32 (padded xyz_)
#define OFF_BASE 2097152u      // 256*256 f32
#define OFF_W2F  2359296u      // 32768 u16  (W2 bf16 B-fragments)
#define OFF_WB   2424832u      // 2048 u16   (head [Wt|Wr|0] B-fragments)
#define WS_NEED  2428928u

__device__ __forceinline__ float fast_gelu(float x) {
    // tanh-gelu via sigmoid: x * sigmoid(2*0.79788456*(x+0.044715x^3))
    float t = x * x;
    float m = x * fmaf(t, -0.10294325f, -2.30220820f);   // -log2(e)*2u
    float e = __builtin_amdgcn_exp2f(m);
    return x * __builtin_amdgcn_rcpf(1.0f + e);
}

__device__ __forceinline__ unsigned short bf_bits(float x) {
    union { float f; unsigned u; } c; c.f = x;
    unsigned r = c.u + 0x7FFFu + ((c.u >> 16) & 1u);   // RTNE
    return (unsigned short)(r >> 16);
}

// ======================= prep kernel (257 blocks) =======================
__global__ __launch_bounds__(NTHREADS, 2)
void prep_kernel(const float* __restrict__ SF, const float* __restrict__ Q,
                 const float* __restrict__ TR, const float* __restrict__ W1,
                 const float* __restrict__ b1, const float* __restrict__ W2,
                 const float* __restrict__ Wt, const float* __restrict__ Wr,
                 float* __restrict__ wsLrp, float* __restrict__ wsBase,
                 unsigned short* __restrict__ wsW2f, unsigned short* __restrict__ wsWB)
{
    const int g = blockIdx.x;
    const int t = threadIdx.x;

    if (g == GB) {
        // W2 -> bf16 B-fragments: [(wv*8+ks)*64 + lane] * 8
        for (int idx = t; idx < 4096; idx += NTHREADS) {
            int pair = idx >> 6, lane = idx & 63;
            int wv2 = pair >> 3, ks = pair & 7;
            int ln = lane & 15, lq = lane >> 4;
            int col = (wv2 << 4) | ln;
            u16x8 tmp;
            #pragma unroll
            for (int i = 0; i < 8; ++i)
                tmp[i] = bf_bits(W2[(ks * 32 + lq * 8 + i) * DH + col]);
            *(u16x8*)&wsW2f[idx * 8] = tmp;
        }
        // head [Wt|Wr|0-pad] -> bf16 B-fragments, 4 K-steps
        for (int idx = t; idx < 2048; idx += NTHREADS) {
            int ks = idx >> 9, rem = idx & 511;
            int lane = rem >> 3, i = rem & 7;
            int bq = (lane >> 4) & 3, bn = lane & 15;
            int k = ks * 32 + bq * 8 + i;
            float v = (bn < 3) ? Wt[k * 3 + bn] : (bn < 6 ? Wr[k * 3 + bn - 3] : 0.0f);
            wsWB[idx] = bf_bits(v);
        }
        return;
    }

    __shared__ float sRed[8][4];
    __shared__ float sCent[3];
    __shared__ float sS[DD];
    __shared__ float sPart[NTHREADS];

    // centroid: wave shfl reduce
    const float* trp = TR + ((size_t)g * RR + t) * 3;
    float sx = trp[0], sy = trp[1], sz = trp[2];
    float rx = sx, ry = sy, rz = sz;
    #pragma unroll
    for (int d = 1; d < 64; d <<= 1) {
        sx += __shfl_xor(sx, d); sy += __shfl_xor(sy, d); sz += __shfl_xor(sz, d);
    }
    const int wv = t >> 6, wl = t & 63;
    if (wl == 0) { sRed[wv][0] = sx; sRed[wv][1] = sy; sRed[wv][2] = sz; }
    if (t < DD) sS[t] = SF[g * DD + t];
    __syncthreads();
    if (t == 0) {
        float cx = 0, cy = 0, cz = 0;
        #pragma unroll
        for (int i = 0; i < 8; ++i) { cx += sRed[i][0]; cy += sRed[i][1]; cz += sRed[i][2]; }
        sCent[0] = cx * (1.0f / RR); sCent[1] = cy * (1.0f / RR); sCent[2] = cz * (1.0f / RR);
    }
    __syncthreads();

    // local_rel_pos (conjugate rotation), padded float4
    {
        const float4 q = ((const float4*)Q)[(size_t)g * RR + t];
        float ax = rx - sCent[0], ay = ry - sCent[1], az = rz - sCent[2];
        float qw = q.x, qx = q.y, qy = q.z, qz = q.w;
        float n = sqrtf(qw * qw + qx * qx + qy * qy + qz * qz) + 1e-8f;
        float inv = 1.0f / n;
        float nw = qw * inv, nx = qx * inv, ny = qy * inv, nz = qz * inv;
        float xx = nx * nx, yy = ny * ny, zz = nz * nz;
        float xy = nx * ny, xz = nx * nz, yz = ny * nz;
        float wx = nw * nx, wy = nw * ny, wz = nw * nz;
        float m00 = 1.f - 2.f * (yy + zz), m01 = 2.f * (xy - wz), m02 = 2.f * (xz + wy);
        float m10 = 2.f * (xy + wz), m11 = 1.f - 2.f * (xx + zz), m12 = 2.f * (yz - wx);
        float m20 = 2.f * (xz - wy), m21 = 2.f * (yz + wx), m22 = 1.f - 2.f * (xx + yy);
        float4 o;
        o.x = m00 * ax + m10 * ay + m20 * az;
        o.y = m01 * ax + m11 * ay + m21 * az;
        o.z = m02 * ax + m12 * ay + m22 * az;
        o.w = 0.0f;
        ((float4*)wsLrp)[(size_t)g * RR + t] = o;
    }

    // base = s @ W1[:256] + b1
    {
        const int j = t & 255;
        const int half = t >> 8;
        float acc = 0.0f;
        const int k0 = half * 128;
        for (int k = k0; k < k0 + 128; ++k)
            acc += sS[k] * W1[k * DD + j];
        sPart[t] = acc;
        __syncthreads();
        if (t < DD) wsBase[g * DD + t] = sPart[t] + sPart[DD + t] + b1[t];
    }
}

// ======================= main kernel (2048 blocks, 64 rods each) =======================
__global__ __launch_bounds__(NTHREADS, 6)
void main_kernel(const float* __restrict__ Q, const float* __restrict__ W1,
                 const float* __restrict__ b2, const float* __restrict__ bt,
                 const float* __restrict__ br,
                 const float* __restrict__ wsLrp, const float* __restrict__ wsBase,
                 const unsigned short* __restrict__ wsW2f,
                 const unsigned short* __restrict__ wsWB,
                 float* __restrict__ out)
{
    __shared__ unsigned short sH1u[64 * 264];   // 33792 B, aliased with h2 (stride 136)
    __shared__ unsigned short sWB[2048];        // 4096 B
    __shared__ float sDot[64][6];               // 1536 B

    const int bx = blockIdx.x;
    const int g = bx >> 3;
    const int r0 = (bx & 7) << 6;
    const int t = threadIdx.x;
    const int wv = t >> 6, wl = t & 63, ln = t & 15, lq = (t >> 4) & 3;
    const int colN = (wv << 4) | ln;
    unsigned short* sH2b = sH1u;                // alias

    // stage head-B fragments
    if (t < 256) ((uint4*)sWB)[t] = ((const uint4*)wsWB)[t];

    // W2 B-fragments -> registers (coalesced b128 loads)
    bf16x8 Breg[8];
    #pragma unroll
    for (int ks = 0; ks < 8; ++ks)
        Breg[ks] = *(const bf16x8*)&wsW2f[((wv * 8 + ks) * 64 + wl) * 8];

    // per-lane phase-2 column data (4 consecutive cols per lane)
    const int l4 = wl * 4;
    const float4 base4 = *(const float4*)&wsBase[g * DD + l4];
    const float4 w1ta = *(const float4*)&W1[256 * DD + l4];
    const float4 w1tb = *(const float4*)&W1[257 * DD + l4];
    const float4 w1tc = *(const float4*)&W1[258 * DD + l4];
    const float bb = b2[colN];

    // phase 2: h1 = gelu(base + lrp.W1tail); wave wv owns rows wv*8..+8
    #pragma unroll
    for (int it = 0; it < 8; ++it) {
        int row = wv * 8 + it;
        float4 l = ((const float4*)wsLrp)[(size_t)g * RR + r0 + row];  // broadcast
        float v0 = base4.x + l.x * w1ta.x + l.y * w1tb.x + l.z * w1tc.x;
        float v1 = base4.y + l.x * w1ta.y + l.y * w1tb.y + l.z * w1tc.y;
        float v2 = base4.z + l.x * w1ta.z + l.y * w1tb.z + l.z * w1tc.z;
        float v3 = base4.w + l.x * w1ta.w + l.y * w1tb.w + l.z * w1tc.w;
        unsigned p0 = (unsigned)bf_bits(fast_gelu(v0)) | ((unsigned)bf_bits(fast_gelu(v1)) << 16);
        unsigned p1 = (unsigned)bf_bits(fast_gelu(v2)) | ((unsigned)bf_bits(fast_gelu(v3)) << 16);
        uint2 pk; pk.x = p0; pk.y = p1;
        *(uint2*)&sH1u[row * 264 + l4] = pk;
    }
    __syncthreads();

    // phase 3: MFMA h1(64x256) @ W2(256x128); wave wv -> cols [16wv, 16wv+16)
    f32x4 acc0 = {0.f, 0.f, 0.f, 0.f};
    f32x4 acc1 = {0.f, 0.f, 0.f, 0.f};
    f32x4 acc2 = {0.f, 0.f, 0.f, 0.f};
    f32x4 acc3 = {0.f, 0.f, 0.f, 0.f};
    {
        const unsigned short* aBase = sH1u + ln * 264 + lq * 8;
        #pragma unroll
        for (int ks = 0; ks < 8; ++ks) {
            bf16x8 b = Breg[ks];
            bf16x8 a0 = *(const bf16x8*)(aBase + ks * 32);
            bf16x8 a1 = *(const bf16x8*)(aBase + 16 * 264 + ks * 32);
            bf16x8 a2 = *(const bf16x8*)(aBase + 32 * 264 + ks * 32);
            bf16x8 a3 = *(const bf16x8*)(aBase + 48 * 264 + ks * 32);
            acc0 = __builtin_amdgcn_mfma_f32_16x16x32_bf16(a0, b, acc0, 0, 0, 0);
            acc1 = __builtin_amdgcn_mfma_f32_16x16x32_bf16(a1, b, acc1, 0, 0, 0);
            acc2 = __builtin_amdgcn_mfma_f32_16x16x32_bf16(a2, b, acc2, 0, 0, 0);
            ac3:
            acc3 = __builtin_amdgcn_mfma_f32_16x16x32_bf16(a3, b, acc3, 0, 0, 0);
        }
    }
    __syncthreads();   // all h1 reads done before aliased h2 writes

    // h2 = gelu(D + b2) -> bf16 into aliased buffer (stride 136)
    #pragma unroll
    for (int r = 0; r < 4; ++r) {
        int rq = lq * 4 + r;
        sH2b[(rq)      * 136 + colN] = bf_bits(fast_gelu(acc0[r] + bb));
        sH2b[(rq + 16) * 136 + colN] = bf_bits(fast_gelu(acc1[r] + bb));
        sH2b[(rq + 32) * 136 + colN] = bf_bits(fast_gelu(acc2[r] + bb));
        sH2b[(rq + 48) * 136 + colN] = bf_bits(fast_gelu(acc3[r] + bb));
    }
    __syncthreads();

    // head + epilogue: waves 0..3 own rows 16wv..16wv+16; no further barriers
    if (wv < 4) {
        f32x4 dacc = {0.f, 0.f, 0.f, 0.f};
        const unsigned short* aB = sH2b + (wv * 16 + ln) * 136 + lq * 8;
        #pragma unroll
        for (int ks = 0; ks < 4; ++ks) {
            bf16x8 a = *(const bf16x8*)(aB + ks * 32);
            bf16x8 b = *(const bf16x8*)(&sWB[ks * 512 + wl * 8]);
            dacc = __builtin_amdgcn_mfma_f32_16x16x32_bf16(a, b, dacc, 0, 0, 0);
        }
        if (ln < 6) {
            #pragma unroll
            for (int r = 0; r < 4; ++r)
                sDot[wv * 16 + lq * 4 + r][ln] = dacc[r];
        }
        // wave-local ds write -> ds read: lgkmcnt handles ordering
        if (wl < 16) {
            int row = wv * 16 + wl;
            float4 q = ((const float4*)Q)[(size_t)g * RR + r0 + row];
            float qw = q.x, qx = q.y, qy = q.z, qz = q.w;
            float n = sqrtf(qw * qw + qx * qx + qy * qy + qz * qz) + 1e-8f;
            float inv = 1.0f / n;
            float nw = qw * inv, nx = qx * inv, ny = qy * inv, nz = qz * inv;
            float tvp0 = sDot[row][0] + bt[0];
            float tvp1 = sDot[row][1] + bt[1];
            float tvp2 = sDot[row][2] + bt[2];
            float rv0 = (sDot[row][3] + br[0]) * 0.1f;
            float rv1 = (sDot[row][4] + br[1]) * 0.1f;
            float rv2 = (sDot[row][5] + br[2]) * 0.1f;
            float xx = nx * nx, yy = ny * ny, zz = nz * nz;
            float xy = nx * ny, xz = nx * nz, yz = ny * nz;
            float wx = nw * nx, wy = nw * ny, wz = nw * nz;
            float m00 = 1.f - 2.f * (yy + zz), m01 = 2.f * (xy - wz), m02 = 2.f * (xz + wy);
            float m10 = 2.f * (xy + wz), m11 = 1.f - 2.f * (xx + zz), m12 = 2.f * (yz - wx);
            float m20 = 2.f * (xz - wy), m21 = 2.f * (yz + wx), m22 = 1.f - 2.f * (xx + yy);
            float tv0 = m00 * tvp0 + m01 * tvp1 + m02 * tvp2;
            float tv1 = m10 * tvp0 + m11 * tvp1 + m12 * tvp2;
            float tv2 = m20 * tvp0 + m21 * tvp1 + m22 * tvp2;
            float* op = out + ((size_t)g * RR + r0 + row) * 7;
            op[0] = -0.5f * (qx * rv0 + qy * rv1 + qz * rv2);
            op[1] =  0.5f * (qw * rv0 + qy * rv2 - qz * rv1);
            op[2] =  0.5f * (qw * rv1 - qx * rv2 + qz * rv0);
            op[3] =  0.5f * (qw * rv2 + qx * rv1 - qy * rv0);
            op[4] = tv0; op[5] = tv1; op[6] = tv2;
        }
    }
}

// ======================= fallback (R3 single-kernel) =======================
__global__ __launch_bounds__(NTHREADS, 4)
void eq_head_fallback(const float* __restrict__ SF, const float* __restrict__ Q,
                      const float* __restrict__ TR, const float* __restrict__ W1,
                      const float* __restrict__ b1, const float* __restrict__ W2,
                      const float* __restrict__ b2, const float* __restrict__ Wt,
                      const float* __restrict__ bt, const float* __restrict__ Wr,
                      const float* __restrict__ br, float* __restrict__ out)
{
    __shared__ char sBuf[64 * 264 * 2];
    __shared__ float sLrp[RR][3];
    __shared__ float sS[DD];
    __shared__ float sW1t[3][DD];
    __shared__ float sBase[DD];
    __shared__ float sB2[DH];
    __shared__ unsigned short sWB[4 * 512];
    __shared__ float sDot[64][6];
    __shared__ float sCent[3];
    __shared__ float sBt[3];
    __shared__ float sBr[3];

    unsigned short* sH1u = (unsigned short*)sBuf;
    unsigned short* sH2b = (unsigned short*)sBuf;
    float* scratch = (float*)sBuf;

    const int g = blockIdx.x;
    const int t = threadIdx.x;
    const int wv = t >> 6, wl = t & 63, ln = t & 15, lq = (t >> 4) & 3;
    const int colN = (wv << 4) + ln;

    if (t < DD) sS[t] = SF[g * DD + t];
    for (int idx = t; idx < 3 * DD; idx += NTHREADS)
        ((float*)sW1t)[idx] = W1[DD * DD + idx];
    if (t < DH) sB2[t] = b2[t];
    if (t < 3) { sBt[t] = bt[t]; sBr[t] = br[t]; }
    for (int idx = t; idx < 2048; idx += NTHREADS) {
        int ks = idx >> 9, rem = idx & 511;
        int lane = rem >> 3, i = rem & 7;
        int bq = (lane >> 4) & 3, bn = lane & 15;
        int k = ks * 32 + bq * 8 + i;
        float v = (bn < 3) ? Wt[k * 3 + bn] : (bn < 6 ? Wr[k * 3 + bn - 3] : 0.0f);
        sWB[idx] = bf_bits(v);
    }
    {
        const float* trp = TR + ((size_t)g * RR + t) * 3;
        scratch[t] = trp[0]; scratch[512 + t] = trp[1]; scratch[1024 + t] = trp[2];
    }
    __syncthreads();
    for (int s = 256; s > 0; s >>= 1) {
        if (t < s) {
            scratch[t] += scratch[t + s];
            scratch[512 + t] += scratch[512 + t + s];
            scratch[1024 + t] += scratch[1024 + t + s];
        }
        __syncthreads();
    }
    if (t < 3) sCent[t] = scratch[t * 512] * (1.0f / RR);
    __syncthreads();
    {
        const float4 q = ((const float4*)Q)[(size_t)g * RR + t];
        const float* trp = TR + ((size_t)g * RR + t) * 3;
        float rx = trp[0] - sCent[0], ry = trp[1] - sCent[1], rz = trp[2] - sCent[2];
        float qw = q.x, qx = q.y, qy = q.z, qz = q.w;
        float n = sqrtf(qw * qw + qx * qx + qy * qy + qz * qz) + 1e-8f;
        float inv = 1.0f / n;
        float nw = qw * inv, nx = qx * inv, ny = qy * inv, nz = qz * inv;
        float xx = nx * nx, yy = ny * ny, zz = nz * nz;
        float xy = nx * ny, xz = nx * nz, yz = ny * nz;
        float wx = nw * nx, wy = nw * ny, wz = nw * nz;
        float m00 = 1.f - 2.f * (yy + zz), m01 = 2.f * (xy - wz), m02 = 2.f * (xz + wy);
        float m10 = 2.f * (xy + wz), m11 = 1.f - 2.f * (xx + zz), m12 = 2.f * (yz - wx);
        float m20 = 2.f * (xz - wy), m21 = 2.f * (yz + wx), m22 = 1.f - 2.f * (xx + yy);
        sLrp[t][0] = m00 * rx + m10 * ry + m20 * rz;
        sLrp[t][1] = m01 * rx + m11 * ry + m21 * rz;
        sLrp[t][2] = m02 * rx + m12 * ry + m22 * rz;
    }
    {
        const int j = t & 255, half = t >> 8;
        float acc0 = 0.0f;
        for (int k = half * 128; k < half * 128 + 128; ++k)
            acc0 += sS[k] * W1[k * DD + j];
        __syncthreads();
        scratch[t] = acc0;
        __syncthreads();
        if (t < DD) sBase[t] = scratch[t] + scratch[DD + t] + b1[t];
    }
    bf16x8 Breg[8];
    #pragma unroll
    for (int ks = 0; ks < 8; ++ks) {
        u16x8 tmp;
        #pragma unroll
        for (int i = 0; i < 8; ++i)
            tmp[i] = bf_bits(W2[(ks * 32 + lq * 8 + i) * DH + colN]);
        Breg[ks] = __builtin_bit_cast(bf16x8, tmp);
    }
    __syncthreads();
    const int l4 = wl * 4;
    float4 base4 = *(const float4*)&sBase[l4];
    float4 w1ta = *(const float4*)&sW1t[0][l4];
    float4 w1tb = *(const float4*)&sW1t[1][l4];
    float4 w1tc = *(const float4*)&sW1t[2][l4];
    const float4* Qv = (const float4*)Q + (size_t)g * RR;
    const int cfirst = blockIdx.y * 4;
    for (int cc = 0; cc < 4; ++cc) {
        const int r0 = (cfirst + cc) * 64;
        #pragma unroll
        for (int it = 0; it < 8; ++it) {
            int row = wv * 8 + it;
            float l0 = sLrp[r0 + row][0], l1 = sLrp[r0 + row][1], l2 = sLrp[r0 + row][2];
            float v0 = base4.x + l0 * w1ta.x + l1 * w1tb.x + l2 * w1tc.x;
            float v1 = base4.y + l0 * w1ta.y + l1 * w1tb.y + l2 * w1tc.y;
            float v2 = base4.z + l0 * w1ta.z + l1 * w1tb.z + l2 * w1tc.z;
            float v3 = base4.w + l0 * w1ta.w + l1 * w1tb.w + l2 * w1tc.w;
            unsigned p0 = (unsigned)bf_bits(fast_gelu(v0)) | ((unsigned)bf_bits(fast_gelu(v1)) << 16);
            unsigned p1 = (unsigned)bf_bits(fast_gelu(v2)) | ((unsigned)bf_bits(fast_gelu(v3)) << 16);
            uint2 pk; pk.x = p0; pk.y = p1;
            *(uint2*)&sH1u[row * 264 + l4] = pk;
        }
        __syncthreads();
        f32x4 acc0 = {0,0,0,0}, acc1 = {0,0,0,0}, acc2 = {0,0,0,0}, acc3 = {0,0,0,0};
        {
            const unsigned short* aBase = sH1u + ln * 264 + lq * 8;
            #pragma unroll
            for (int ks = 0; ks < 8; ++ks) {
                bf16x8 b = Breg[ks];
                bf16x8 a0 = *(const bf16x8*)(aBase + ks * 32);
                bf16x8 a1 = *(const bf16x8*)(aBase + 16 * 264 + ks * 32);
                bf16x8 a2 = *(const bf16x8*)(aBase + 32 * 264 + ks * 32);
                bf16x8 a3 = *(const bf16x8*)(aBase + 48 * 264 + ks * 32);
                acc0 = __builtin_amdgcn_mfma_f32_16x16x32_bf16(a0, b, acc0, 0, 0, 0);
                acc1 = __builtin_amdgcn_mfma_f32_16x16x32_bf16(a1, b, acc1, 0, 0, 0);
                acc2 = __builtin_amdgcn_mfma_f32_16x16x32_bf16(a2, b, acc2, 0, 0, 0);
                acc3 = __builtin_amdgcn_mfma_f32_16x16x32_bf16(a3, b, acc3, 0, 0, 0);
            }
        }
        __syncthreads();
        {
            float bb = sB2[colN];
            #pragma unroll
            for (int r = 0; r < 4; ++r) {
                int rq = lq * 4 + r;
                sH2b[(rq) * 136 + colN] = bf_bits(fast_gelu(acc0[r] + bb));
                sH2b[(rq + 16) * 136 + colN] = bf_bits(fast_gelu(acc1[r] + bb));
                sH2b[(rq + 32) * 136 + colN] = bf_bits(fast_gelu(acc2[r] + bb));
                sH2b[(rq + 48) * 136 + colN] = bf_bits(fast_gelu(acc3[r] + bb));
            }
        }
        __syncthreads();
        if (wv < 4) {
            f32x4 dacc = {0,0,0,0};
            const unsigned short* aB = sH2b + (wv * 16 + ln) * 136 + lq * 8;
            #pragma unroll
            for (int ks = 0; ks < 4; ++ks) {
                bf16x8 a = *(const bf16x8*)(aB + ks * 32);
                bf16x8 b = *(const bf16x8*)(&sWB[ks * 512 + wl * 8]);
                dacc = __builtin_amdgcn_mfma_f32_16x16x32_bf16(a, b, dacc, 0, 0, 0);
            }
            if (ln < 6) {
                #pragma unroll
                for (int r = 0; r < 4; ++r)
                    sDot[wv * 16 + lq * 4 + r][ln] = dacc[r];
            }
        }
        __syncthreads();
        if (t < 64) {
            float4 q = Qv[r0 + t];
            float qw = q.x, qx = q.y, qy = q.z, qz = q.w;
            float n = sqrtf(qw * qw + qx * qx + qy * qy + qz * qz) + 1e-8f;
            float inv = 1.0f / n;
            float nw = qw * inv, nx = qx * inv, ny = qy * inv, nz = qz * inv;
            float tvp0 = sDot[t][0] + sBt[0];
            float tvp1 = sDot[t][1] + sBt[1];
            float tvp2 = sDot[t][2] + sBt[2];
            float rv0 = (sDot[t][3] + sBr[0]) * 0.1f;
            float rv1 = (sDot[t][4] + sBr[1]) * 0.1f;
            float rv2 = (sDot[t][5] + sBr[2]) * 0.1f;
            float xx = nx * nx, yy = ny * ny, zz = nz * nz;
            float xy = nx * ny, xz = nx * nz, yz = ny * nz;
            float wx = nw * nx, wy = nw * ny, wz = nw * nz;
            float m00 = 1.f - 2.f * (yy + zz), m01 = 2.f * (xy - wz), m02 = 2.f * (xz + wy);
            float m10 = 2.f * (xy + wz), m11 = 1.f - 2.f * (xx + zz), m12 = 2.f * (yz - wx);
            float m20 = 2.f * (xz - wy), m21 = 2.f * (yz + wx), m22 = 1.f - 2.f * (xx + yy);
            float tv0 = m00 * tvp0 + m01 * tvp1 + m02 * tvp2;
            float tv1 = m10 * tvp0 + m11 * tvp1 + m12 * tvp2;
            float tv2 = m20 * tvp0 + m21 * tvp1 + m22 * tvp2;
            float* op = out + ((size_t)g * RR + r0 + t) * 7;
            op[0] = -0.5f * (qx * rv0 + qy * rv1 + qz * rv2);
            op[1] =  0.5f * (qw * rv0 + qy * rv2 - qz * rv1);
            op[2] =  0.5f * (qw * rv1 - qx * rv2 + qz * rv0);
            op[3] =  0.5f * (qw * rv2 + qx * rv1 - qy * rv0);
            op[4] = tv0; op[5] = tv1; op[6] = tv2;
        }
        __syncthreads();
    }
}

extern "C" void kernel_launch(void* const* d_in, const int* in_sizes, int n_in,
                              void* d_out, int out_size, void* d_ws, size_t ws_size,
                              hipStream_t stream) {
    const float* SF = (const float*)d_in[0];
    const float* Q  = (const float*)d_in[1];
    const float* TR = (const float*)d_in[2];
    const float* W1 = (const float*)d_in[3];
    const float* b1 = (const float*)d_in[4];
    const float* W2 = (const float*)d_in[5];
    const float* b2 = (const float*)d_in[6];
    const float* Wt = (const float*)d_in[7];
    const float* bt = (const float*)d_in[8];
    const float* Wr = (const float*)d_in[9];
    const float* br = (const float*)d_in[10];
    float* out = (float*)d_out;

    if (ws_size >= WS_NEED) {
        char* ws = (char*)d_ws;
        float* wsLrp = (float*)(ws + OFF_LRP);
        float* wsBase = (float*)(ws + OFF_BASE);
        unsigned short* wsW2f = (unsigned short*)(ws + OFF_W2F);
        unsigned short* wsWB = (unsigned short*)(ws + OFF_WB);
        prep_kernel<<<GB + 1, NTHREADS, 0, stream>>>(SF, Q, TR, W1, b1, W2, Wt, Wr,
                                                     wsLrp, wsBase, wsW2f, wsWB);
        main_kernel<<<GB * 8, NTHREADS, 0, stream>>>(Q, W1, b2, bt, br,
                                                     wsLrp, wsBase, wsW2f, wsWB, out);
    } else {
        dim3 grid(GB, 2);
        eq_head_fallback<<<grid, NTHREADS, 0, stream>>>(SF, Q, TR, W1, b1, W2, b2,
                                                        Wt, bt, Wr, br, out);
    }
}

// Round 5
// 108.047 us; speedup vs baseline: 3.5464x; 1.2478x over previous
//
#include <hip/hip_runtime.h>
#include <math.h>

#define GB 256      // B*T groups
#define RR 512      // rods per group
#define DD 256      // D
#define DH 128      // D/2
#define NTHREADS 512

typedef __bf16 bf16x8 __attribute__((ext_vector_type(8)));
typedef unsigned short u16x8 __attribute__((ext_vector_type(8)));
typedef float f32x4 __attribute__((ext_vector_type(4)));

// ws layout (bytes)
#define OFF_LRP  0u            // 256*512*4 f32 (padded xyz_)
#define OFF_BASE 2097152u      // 256*256 f32
#define OFF_W2F  2359296u      // 32768 u16  (W2 bf16 B-fragments)
#define OFF_WB   2424832u      // 2048 u16   (head [Wt|Wr|0] B-fragments)
#define WS_NEED  2428928u

__device__ __forceinline__ float fast_gelu(float x) {
    // tanh-gelu via sigmoid: x * sigmoid(2*0.79788456*(x+0.044715x^3))
    float t = x * x;
    float m = x * fmaf(t, -0.10294325f, -2.30220820f);   // -log2(e)*2u
    float e = __builtin_amdgcn_exp2f(m);
    return x * __builtin_amdgcn_rcpf(1.0f + e);
}

__device__ __forceinline__ unsigned short bf_bits(float x) {
    union { float f; unsigned u; } c; c.f = x;
    unsigned r = c.u + 0x7FFFu + ((c.u >> 16) & 1u);   // RTNE
    return (unsigned short)(r >> 16);
}

// ======================= prep kernel (513 blocks) =======================
// blocks 0..255   : centroid + local_rel_pos for group bx
// blocks 256..511 : base = s @ W1[:256] + b1 for group bx-256  (ILP-pipelined)
// block  512      : W2 + head weight fragments (bf16, MFMA layout)
__global__ __launch_bounds__(NTHREADS, 2)
void prep_kernel(const float* __restrict__ SF, const float* __restrict__ Q,
                 const float* __restrict__ TR, const float* __restrict__ W1,
                 const float* __restrict__ b1, const float* __restrict__ W2,
                 const float* __restrict__ Wt, const float* __restrict__ Wr,
                 float* __restrict__ wsLrp, float* __restrict__ wsBase,
                 unsigned short* __restrict__ wsW2f, unsigned short* __restrict__ wsWB)
{
    const int bx = blockIdx.x;
    const int t = threadIdx.x;

    if (bx < GB) {
        // ---------- centroid + LRP ----------
        const int g = bx;
        __shared__ float sRed[8][4];
        __shared__ float sCent[3];

        const float* trp = TR + ((size_t)g * RR + t) * 3;
        float sx = trp[0], sy = trp[1], sz = trp[2];
        float rx = sx, ry = sy, rz = sz;
        #pragma unroll
        for (int d = 1; d < 64; d <<= 1) {
            sx += __shfl_xor(sx, d); sy += __shfl_xor(sy, d); sz += __shfl_xor(sz, d);
        }
        const int wv = t >> 6, wl = t & 63;
        if (wl == 0) { sRed[wv][0] = sx; sRed[wv][1] = sy; sRed[wv][2] = sz; }
        __syncthreads();
        if (t == 0) {
            float cx = 0, cy = 0, cz = 0;
            #pragma unroll
            for (int i = 0; i < 8; ++i) { cx += sRed[i][0]; cy += sRed[i][1]; cz += sRed[i][2]; }
            sCent[0] = cx * (1.0f / RR); sCent[1] = cy * (1.0f / RR); sCent[2] = cz * (1.0f / RR);
        }
        __syncthreads();

        const float4 q = ((const float4*)Q)[(size_t)g * RR + t];
        float ax = rx - sCent[0], ay = ry - sCent[1], az = rz - sCent[2];
        float qw = q.x, qx = q.y, qy = q.z, qz = q.w;
        float n = sqrtf(qw * qw + qx * qx + qy * qy + qz * qz) + 1e-8f;
        float inv = 1.0f / n;
        float nw = qw * inv, nx = qx * inv, ny = qy * inv, nz = qz * inv;
        float xx = nx * nx, yy = ny * ny, zz = nz * nz;
        float xy = nx * ny, xz = nx * nz, yz = ny * nz;
        float wx = nw * nx, wy = nw * ny, wz = nw * nz;
        float m00 = 1.f - 2.f * (yy + zz), m01 = 2.f * (xy - wz), m02 = 2.f * (xz + wy);
        float m10 = 2.f * (xy + wz), m11 = 1.f - 2.f * (xx + zz), m12 = 2.f * (yz - wx);
        float m20 = 2.f * (xz - wy), m21 = 2.f * (yz + wx), m22 = 1.f - 2.f * (xx + yy);
        float4 o;
        o.x = m00 * ax + m10 * ay + m20 * az;
        o.y = m01 * ax + m11 * ay + m21 * az;
        o.z = m02 * ax + m12 * ay + m22 * az;
        o.w = 0.0f;
        ((float4*)wsLrp)[(size_t)g * RR + t] = o;

    } else if (bx < 2 * GB) {
        // ---------- base GEMV, ILP-restructured ----------
        const int g = bx - GB;
        __shared__ float sS[DD];
        __shared__ float sPart[8 * DD];   // 8 KB

        if (t < 64) ((float4*)sS)[t] = ((const float4*)(SF + (size_t)g * DD))[t];
        __syncthreads();

        const int jg = t & 63, ks = t >> 6;
        const int j4 = jg * 4, k0 = ks * 32;
        float4 acc = {0.f, 0.f, 0.f, 0.f};
        #pragma unroll 8
        for (int kk = 0; kk < 32; ++kk) {
            float s = sS[k0 + kk];
            float4 w = *(const float4*)&W1[(size_t)(k0 + kk) * DD + j4];
            acc.x = fmaf(s, w.x, acc.x);
            acc.y = fmaf(s, w.y, acc.y);
            acc.z = fmaf(s, w.z, acc.z);
            acc.w = fmaf(s, w.w, acc.w);
        }
        *(float4*)&sPart[ks * DD + j4] = acc;
        __syncthreads();
        if (t < DD) {
            float a = b1[t];
            #pragma unroll
            for (int i = 0; i < 8; ++i) a += sPart[i * DD + t];
            wsBase[(size_t)g * DD + t] = a;
        }

    } else {
        // ---------- weight fragments ----------
        // W2 -> bf16 B-fragments: [(wv*8+ks)*64 + lane] * 8
        #pragma unroll 2
        for (int idx = t; idx < 4096; idx += NTHREADS) {
            int pair = idx >> 6, lane = idx & 63;
            int wv2 = pair >> 3, ks = pair & 7;
            int ln = lane & 15, lq = lane >> 4;
            int col = (wv2 << 4) | ln;
            u16x8 tmp;
            #pragma unroll
            for (int i = 0; i < 8; ++i)
                tmp[i] = bf_bits(W2[(ks * 32 + lq * 8 + i) * DH + col]);
            *(u16x8*)&wsW2f[idx * 8] = tmp;
        }
        // head [Wt|Wr|0-pad] -> bf16 B-fragments, 4 K-steps
        for (int idx = t; idx < 2048; idx += NTHREADS) {
            int ks = idx >> 9, rem = idx & 511;
            int lane = rem >> 3, i = rem & 7;
            int bq = (lane >> 4) & 3, bn = lane & 15;
            int k = ks * 32 + bq * 8 + i;
            float v = (bn < 3) ? Wt[k * 3 + bn] : (bn < 6 ? Wr[k * 3 + bn - 3] : 0.0f);
            wsWB[idx] = bf_bits(v);
        }
    }
}

// ======================= main kernel (2048 blocks, 64 rods each) =======================
__global__ __launch_bounds__(NTHREADS, 6)
void main_kernel(const float* __restrict__ Q, const float* __restrict__ W1,
                 const float* __restrict__ b2, const float* __restrict__ bt,
                 const float* __restrict__ br,
                 const float* __restrict__ wsLrp, const float* __restrict__ wsBase,
                 const unsigned short* __restrict__ wsW2f,
                 const unsigned short* __restrict__ wsWB,
                 float* __restrict__ out)
{
    __shared__ unsigned short sH1u[64 * 264];   // 33792 B, aliased with h2 (stride 136)
    __shared__ unsigned short sWB[2048];        // 4096 B
    __shared__ float sDot[64][6];               // 1536 B

    const int bx = blockIdx.x;
    const int g = bx >> 3;
    const int r0 = (bx & 7) << 6;
    const int t = threadIdx.x;
    const int wv = t >> 6, wl = t & 63, ln = t & 15, lq = (t >> 4) & 3;
    const int colN = (wv << 4) | ln;
    unsigned short* sH2b = sH1u;                // alias

    // stage head-B fragments
    if (t < 256) ((uint4*)sWB)[t] = ((const uint4*)wsWB)[t];

    // W2 B-fragments -> registers (coalesced b128 loads)
    bf16x8 Breg[8];
    #pragma unroll
    for (int ks = 0; ks < 8; ++ks)
        Breg[ks] = *(const bf16x8*)&wsW2f[((wv * 8 + ks) * 64 + wl) * 8];

    // per-lane phase-2 column data (4 consecutive cols per lane)
    const int l4 = wl * 4;
    const float4 base4 = *(const float4*)&wsBase[g * DD + l4];
    const float4 w1ta = *(const float4*)&W1[256 * DD + l4];
    const float4 w1tb = *(const float4*)&W1[257 * DD + l4];
    const float4 w1tc = *(const float4*)&W1[258 * DD + l4];
    const float bb = b2[colN];

    // phase 2: h1 = gelu(base + lrp.W1tail); wave wv owns rows wv*8..+8
    #pragma unroll
    for (int it = 0; it < 8; ++it) {
        int row = wv * 8 + it;
        float4 l = ((const float4*)wsLrp)[(size_t)g * RR + r0 + row];  // broadcast
        float v0 = base4.x + l.x * w1ta.x + l.y * w1tb.x + l.z * w1tc.x;
        float v1 = base4.y + l.x * w1ta.y + l.y * w1tb.y + l.z * w1tc.y;
        float v2 = base4.z + l.x * w1ta.z + l.y * w1tb.z + l.z * w1tc.z;
        float v3 = base4.w + l.x * w1ta.w + l.y * w1tb.w + l.z * w1tc.w;
        unsigned p0 = (unsigned)bf_bits(fast_gelu(v0)) | ((unsigned)bf_bits(fast_gelu(v1)) << 16);
        unsigned p1 = (unsigned)bf_bits(fast_gelu(v2)) | ((unsigned)bf_bits(fast_gelu(v3)) << 16);
        uint2 pk; pk.x = p0; pk.y = p1;
        *(uint2*)&sH1u[row * 264 + l4] = pk;
    }
    __syncthreads();

    // phase 3: MFMA h1(64x256) @ W2(256x128); wave wv -> cols [16wv, 16wv+16)
    f32x4 acc0 = {0.f, 0.f, 0.f, 0.f};
    f32x4 acc1 = {0.f, 0.f, 0.f, 0.f};
    f32x4 acc2 = {0.f, 0.f, 0.f, 0.f};
    f32x4 acc3 = {0.f, 0.f, 0.f, 0.f};
    {
        const unsigned short* aBase = sH1u + ln * 264 + lq * 8;
        #pragma unroll
        for (int ks = 0; ks < 8; ++ks) {
            bf16x8 b = Breg[ks];
            bf16x8 a0 = *(const bf16x8*)(aBase + ks * 32);
            bf16x8 a1 = *(const bf16x8*)(aBase + 16 * 264 + ks * 32);
            bf16x8 a2 = *(const bf16x8*)(aBase + 32 * 264 + ks * 32);
            bf16x8 a3 = *(const bf16x8*)(aBase + 48 * 264 + ks * 32);
            acc0 = __builtin_amdgcn_mfma_f32_16x16x32_bf16(a0, b, acc0, 0, 0, 0);
            acc1 = __builtin_amdgcn_mfma_f32_16x16x32_bf16(a1, b, acc1, 0, 0, 0);
            acc2 = __builtin_amdgcn_mfma_f32_16x16x32_bf16(a2, b, acc2, 0, 0, 0);
            acc3 = __builtin_amdgcn_mfma_f32_16x16x32_bf16(a3, b, acc3, 0, 0, 0);
        }
    }
    __syncthreads();   // all h1 reads done before aliased h2 writes

    // h2 = gelu(D + b2) -> bf16 into aliased buffer (stride 136)
    #pragma unroll
    for (int r = 0; r < 4; ++r) {
        int rq = lq * 4 + r;
        sH2b[(rq)      * 136 + colN] = bf_bits(fast_gelu(acc0[r] + bb));
        sH2b[(rq + 16) * 136 + colN] = bf_bits(fast_gelu(acc1[r] + bb));
        sH2b[(rq + 32) * 136 + colN] = bf_bits(fast_gelu(acc2[r] + bb));
        sH2b[(rq + 48) * 136 + colN] = bf_bits(fast_gelu(acc3[r] + bb));
    }
    __syncthreads();

    // head + epilogue: waves 0..3 own rows 16wv..16wv+16; no further barriers
    if (wv < 4) {
        f32x4 dacc = {0.f, 0.f, 0.f, 0.f};
        const unsigned short* aB = sH2b + (wv * 16 + ln) * 136 + lq * 8;
        #pragma unroll
        for (int ks = 0; ks < 4; ++ks) {
            bf16x8 a = *(const bf16x8*)(aB + ks * 32);
            bf16x8 b = *(const bf16x8*)(&sWB[ks * 512 + wl * 8]);
            dacc = __builtin_amdgcn_mfma_f32_16x16x32_bf16(a, b, dacc, 0, 0, 0);
        }
        if (ln < 6) {
            #pragma unroll
            for (int r = 0; r < 4; ++r)
                sDot[wv * 16 + lq * 4 + r][ln] = dacc[r];
        }
        // wave-local ds write -> ds read: lgkmcnt handles ordering
        if (wl < 16) {
            int row = wv * 16 + wl;
            float4 q = ((const float4*)Q)[(size_t)g * RR + r0 + row];
            float qw = q.x, qx = q.y, qy = q.z, qz = q.w;
            float n = sqrtf(qw * qw + qx * qx + qy * qy + qz * qz) + 1e-8f;
            float inv = 1.0f / n;
            float nw = qw * inv, nx = qx * inv, ny = qy * inv, nz = qz * inv;
            float tvp0 = sDot[row][0] + bt[0];
            float tvp1 = sDot[row][1] + bt[1];
            float tvp2 = sDot[row][2] + bt[2];
            float rv0 = (sDot[row][3] + br[0]) * 0.1f;
            float rv1 = (sDot[row][4] + br[1]) * 0.1f;
            float rv2 = (sDot[row][5] + br[2]) * 0.1f;
            float xx = nx * nx, yy = ny * ny, zz = nz * nz;
            float xy = nx * ny, xz = nx * nz, yz = ny * nz;
            float wx = nw * nx, wy = nw * ny, wz = nw * nz;
            float m00 = 1.f - 2.f * (yy + zz), m01 = 2.f * (xy - wz), m02 = 2.f * (xz + wy);
            float m10 = 2.f * (xy + wz), m11 = 1.f - 2.f * (xx + zz), m12 = 2.f * (yz - wx);
            float m20 = 2.f * (xz - wy), m21 = 2.f * (yz + wx), m22 = 1.f - 2.f * (xx + yy);
            float tv0 = m00 * tvp0 + m01 * tvp1 + m02 * tvp2;
            float tv1 = m10 * tvp0 + m11 * tvp1 + m12 * tvp2;
            float tv2 = m20 * tvp0 + m21 * tvp1 + m22 * tvp2;
            float* op = out + ((size_t)g * RR + r0 + row) * 7;
            op[0] = -0.5f * (qx * rv0 + qy * rv1 + qz * rv2);
            op[1] =  0.5f * (qw * rv0 + qy * rv2 - qz * rv1);
            op[2] =  0.5f * (qw * rv1 - qx * rv2 + qz * rv0);
            op[3] =  0.5f * (qw * rv2 + qx * rv1 - qy * rv0);
            op[4] = tv0; op[5] = tv1; op[6] = tv2;
        }
    }
}

// ======================= fallback (single-kernel, no ws) =======================
__global__ __launch_bounds__(NTHREADS, 4)
void eq_head_fallback(const float* __restrict__ SF, const float* __restrict__ Q,
                      const float* __restrict__ TR, const float* __restrict__ W1,
                      const float* __restrict__ b1, const float* __restrict__ W2,
                      const float* __restrict__ b2, const float* __restrict__ Wt,
                      const float* __restrict__ bt, const float* __restrict__ Wr,
                      const float* __restrict__ br, float* __restrict__ out)
{
    __shared__ char sBuf[64 * 264 * 2];
    __shared__ float sLrp[RR][3];
    __shared__ float sS[DD];
    __shared__ float sW1t[3][DD];
    __shared__ float sBase[DD];
    __shared__ float sB2[DH];
    __shared__ unsigned short sWB[4 * 512];
    __shared__ float sDot[64][6];
    __shared__ float sCent[3];
    __shared__ float sBt[3];
    __shared__ float sBr[3];

    unsigned short* sH1u = (unsigned short*)sBuf;
    unsigned short* sH2b = (unsigned short*)sBuf;
    float* scratch = (float*)sBuf;

    const int g = blockIdx.x;
    const int t = threadIdx.x;
    const int wv = t >> 6, wl = t & 63, ln = t & 15, lq = (t >> 4) & 3;
    const int colN = (wv << 4) + ln;

    if (t < DD) sS[t] = SF[g * DD + t];
    for (int idx = t; idx < 3 * DD; idx += NTHREADS)
        ((float*)sW1t)[idx] = W1[DD * DD + idx];
    if (t < DH) sB2[t] = b2[t];
    if (t < 3) { sBt[t] = bt[t]; sBr[t] = br[t]; }
    for (int idx = t; idx < 2048; idx += NTHREADS) {
        int ks = idx >> 9, rem = idx & 511;
        int lane = rem >> 3, i = rem & 7;
        int bq = (lane >> 4) & 3, bn = lane & 15;
        int k = ks * 32 + bq * 8 + i;
        float v = (bn < 3) ? Wt[k * 3 + bn] : (bn < 6 ? Wr[k * 3 + bn - 3] : 0.0f);
        sWB[idx] = bf_bits(v);
    }
    {
        const float* trp = TR + ((size_t)g * RR + t) * 3;
        scratch[t] = trp[0]; scratch[512 + t] = trp[1]; scratch[1024 + t] = trp[2];
    }
    __syncthreads();
    for (int s = 256; s > 0; s >>= 1) {
        if (t < s) {
            scratch[t] += scratch[t + s];
            scratch[512 + t] += scratch[512 + t + s];
            scratch[1024 + t] += scratch[1024 + t + s];
        }
        __syncthreads();
    }
    if (t < 3) sCent[t] = scratch[t * 512] * (1.0f / RR);
    __syncthreads();
    {
        const float4 q = ((const float4*)Q)[(size_t)g * RR + t];
        const float* trp = TR + ((size_t)g * RR + t) * 3;
        float rx = trp[0] - sCent[0], ry = trp[1] - sCent[1], rz = trp[2] - sCent[2];
        float qw = q.x, qx = q.y, qy = q.z, qz = q.w;
        float n = sqrtf(qw * qw + qx * qx + qy * qy + qz * qz) + 1e-8f;
        float inv = 1.0f / n;
        float nw = qw * inv, nx = qx * inv, ny = qy * inv, nz = qz * inv;
        float xx = nx * nx, yy = ny * ny, zz = nz * nz;
        float xy = nx * ny, xz = nx * nz, yz = ny * nz;
        float wx = nw * nx, wy = nw * ny, wz = nw * nz;
        float m00 = 1.f - 2.f * (yy + zz), m01 = 2.f * (xy - wz), m02 = 2.f * (xz + wy);
        float m10 = 2.f * (xy + wz), m11 = 1.f - 2.f * (xx + zz), m12 = 2.f * (yz - wx);
        float m20 = 2.f * (xz - wy), m21 = 2.f * (yz + wx), m22 = 1.f - 2.f * (xx + yy);
        sLrp[t][0] = m00 * rx + m10 * ry + m20 * rz;
        sLrp[t][1] = m01 * rx + m11 * ry + m21 * rz;
        sLrp[t][2] = m02 * rx + m12 * ry + m22 * rz;
    }
    {
        const int j = t & 255, half = t >> 8;
        float acc0 = 0.0f;
        for (int k = half * 128; k < half * 128 + 128; ++k)
            acc0 += sS[k] * W1[k * DD + j];
        __syncthreads();
        scratch[t] = acc0;
        __syncthreads();
        if (t < DD) sBase[t] = scratch[t] + scratch[DD + t] + b1[t];
    }
    bf16x8 Breg[8];
    #pragma unroll
    for (int ks = 0; ks < 8; ++ks) {
        u16x8 tmp;
        #pragma unroll
        for (int i = 0; i < 8; ++i)
            tmp[i] = bf_bits(W2[(ks * 32 + lq * 8 + i) * DH + colN]);
        Breg[ks] = __builtin_bit_cast(bf16x8, tmp);
    }
    __syncthreads();
    const int l4 = wl * 4;
    float4 base4 = *(const float4*)&sBase[l4];
    float4 w1ta = *(const float4*)&sW1t[0][l4];
    float4 w1tb = *(const float4*)&sW1t[1][l4];
    float4 w1tc = *(const float4*)&sW1t[2][l4];
    const float4* Qv = (const float4*)Q + (size_t)g * RR;
    const int cfirst = blockIdx.y * 4;
    for (int cc = 0; cc < 4; ++cc) {
        const int r0 = (cfirst + cc) * 64;
        #pragma unroll
        for (int it = 0; it < 8; ++it) {
            int row = wv * 8 + it;
            float l0 = sLrp[r0 + row][0], l1 = sLrp[r0 + row][1], l2 = sLrp[r0 + row][2];
            float v0 = base4.x + l0 * w1ta.x + l1 * w1tb.x + l2 * w1tc.x;
            float v1 = base4.y + l0 * w1ta.y + l1 * w1tb.y + l2 * w1tc.y;
            float v2 = base4.z + l0 * w1ta.z + l1 * w1tb.z + l2 * w1tc.z;
            float v3 = base4.w + l0 * w1ta.w + l1 * w1tb.w + l2 * w1tc.w;
            unsigned p0 = (unsigned)bf_bits(fast_gelu(v0)) | ((unsigned)bf_bits(fast_gelu(v1)) << 16);
            unsigned p1 = (unsigned)bf_bits(fast_gelu(v2)) | ((unsigned)bf_bits(fast_gelu(v3)) << 16);
            uint2 pk; pk.x = p0; pk.y = p1;
            *(uint2*)&sH1u[row * 264 + l4] = pk;
        }
        __syncthreads();
        f32x4 acc0 = {0,0,0,0}, acc1 = {0,0,0,0}, acc2 = {0,0,0,0}, acc3 = {0,0,0,0};
        {
            const unsigned short* aBase = sH1u + ln * 264 + lq * 8;
            #pragma unroll
            for (int ks = 0; ks < 8; ++ks) {
                bf16x8 b = Breg[ks];
                bf16x8 a0 = *(const bf16x8*)(aBase + ks * 32);
                bf16x8 a1 = *(const bf16x8*)(aBase + 16 * 264 + ks * 32);
                bf16x8 a2 = *(const bf16x8*)(aBase + 32 * 264 + ks * 32);
                bf16x8 a3 = *(const bf16x8*)(aBase + 48 * 264 + ks * 32);
                acc0 = __builtin_amdgcn_mfma_f32_16x16x32_bf16(a0, b, acc0, 0, 0, 0);
                acc1 = __builtin_amdgcn_mfma_f32_16x16x32_bf16(a1, b, acc1, 0, 0, 0);
                acc2 = __builtin_amdgcn_mfma_f32_16x16x32_bf16(a2, b, acc2, 0, 0, 0);
                acc3 = __builtin_amdgcn_mfma_f32_16x16x32_bf16(a3, b, acc3, 0, 0, 0);
            }
        }
        __syncthreads();
        {
            float bb = sB2[colN];
            #pragma unroll
            for (int r = 0; r < 4; ++r) {
                int rq = lq * 4 + r;
                sH2b[(rq) * 136 + colN] = bf_bits(fast_gelu(acc0[r] + bb));
                sH2b[(rq + 16) * 136 + colN] = bf_bits(fast_gelu(acc1[r] + bb));
                sH2b[(rq + 32) * 136 + colN] = bf_bits(fast_gelu(acc2[r] + bb));
                sH2b[(rq + 48) * 136 + colN] = bf_bits(fast_gelu(acc3[r] + bb));
            }
        }
        __syncthreads();
        if (wv < 4) {
            f32x4 dacc = {0,0,0,0};
            const unsigned short* aB = sH2b + (wv * 16 + ln) * 136 + lq * 8;
            #pragma unroll
            for (int ks = 0; ks < 4; ++ks) {
                bf16x8 a = *(const bf16x8*)(aB + ks * 32);
                bf16x8 b = *(const bf16x8*)(&sWB[ks * 512 + wl * 8]);
                dacc = __builtin_amdgcn_mfma_f32_16x16x32_bf16(a, b, dacc, 0, 0, 0);
            }
            if (ln < 6) {
                #pragma unroll
                for (int r = 0; r < 4; ++r)
                    sDot[wv * 16 + lq * 4 + r][ln] = dacc[r];
            }
        }
        __syncthreads();
        if (t < 64) {
            float4 q = Qv[r0 + t];
            float qw = q.x, qx = q.y, qy = q.z, qz = q.w;
            float n = sqrtf(qw * qw + qx * qx + qy * qy + qz * qz) + 1e-8f;
            float inv = 1.0f / n;
            float nw = qw * inv, nx = qx * inv, ny = qy * inv, nz = qz * inv;
            float tvp0 = sDot[t][0] + sBt[0];
            float tvp1 = sDot[t][1] + sBt[1];
            float tvp2 = sDot[t][2] + sBt[2];
            float rv0 = (sDot[t][3] + sBr[0]) * 0.1f;
            float rv1 = (sDot[t][4] + sBr[1]) * 0.1f;
            float rv2 = (sDot[t][5] + sBr[2]) * 0.1f;
            float xx = nx * nx, yy = ny * ny, zz = nz * nz;
            float xy = nx * ny, xz = nx * nz, yz = ny * nz;
            float wx = nw * nx, wy = nw * ny, wz = nw * nz;
            float m00 = 1.f - 2.f * (yy + zz), m01 = 2.f * (xy - wz), m02 = 2.f * (xz + wy);
            float m10 = 2.f * (xy + wz), m11 = 1.f - 2.f * (xx + zz), m12 = 2.f * (yz - wx);
            float m20 = 2.f * (xz - wy), m21 = 2.f * (yz + wx), m22 = 1.f - 2.f * (xx + yy);
            float tv0 = m00 * tvp0 + m01 * tvp1 + m02 * tvp2;
            float tv1 = m10 * tvp0 + m11 * tvp1 + m12 * tvp2;
            float tv2 = m20 * tvp0 + m21 * tvp1 + m22 * tvp2;
            float* op = out + ((size_t)g * RR + r0 + t) * 7;
            op[0] = -0.5f * (qx * rv0 + qy * rv1 + qz * rv2);
            op[1] =  0.5f * (qw * rv0 + qy * rv2 - qz * rv1);
            op[2] =  0.5f * (qw * rv1 - qx * rv2 + qz * rv0);
            op[3] =  0.5f * (qw * rv2 + qx * rv1 - qy * rv0);
            op[4] = tv0; op[5] = tv1; op[6] = tv2;
        }
        __syncthreads();
    }
}

extern "C" void kernel_launch(void* const* d_in, const int* in_sizes, int n_in,
                              void* d_out, int out_size, void* d_ws, size_t ws_size,
                              hipStream_t stream) {
    const float* SF = (const float*)d_in[0];
    const float* Q  = (const float*)d_in[1];
    const float* TR = (const float*)d_in[2];
    const float* W1 = (const float*)d_in[3];
    const float* b1 = (const float*)d_in[4];
    const float* W2 = (const float*)d_in[5];
    const float* b2 = (const float*)d_in[6];
    const float* Wt = (const float*)d_in[7];
    const float* bt = (const float*)d_in[8];
    const float* Wr = (const float*)d_in[9];
    const float* br = (const float*)d_in[10];
    float* out = (float*)d_out;

    if (ws_size >= WS_NEED) {
        char* ws = (char*)d_ws;
        float* wsLrp = (float*)(ws + OFF_LRP);
        float* wsBase = (float*)(ws + OFF_BASE);
        unsigned short* wsW2f = (unsigned short*)(ws + OFF_W2F);
        unsigned short* wsWB = (unsigned short*)(ws + OFF_WB);
        prep_kernel<<<2 * GB + 1, NTHREADS, 0, stream>>>(SF, Q, TR, W1, b1, W2, Wt, Wr,
                                                         wsLrp, wsBase, wsW2f, wsWB);
        main_kernel<<<GB * 8, NTHREADS, 0, stream>>>(Q, W1, b2, bt, br,
                                                     wsLrp, wsBase, wsW2f, wsWB, out);
    } else {
        dim3 grid(GB, 2);
        eq_head_fallback<<<grid, NTHREADS, 0, stream>>>(SF, Q, TR, W1, b1, W2, b2,
                                                        Wt, bt, Wr, br, out);
    }
}

// Round 6
// 107.595 us; speedup vs baseline: 3.5613x; 1.0042x over previous
//
#include <hip/hip_runtime.h>
#include <math.h>

#define GB 256      // B*T groups
#define RR 512      // rods per group
#define DD 256      // D
#define DH 128      // D/2
#define NTHREADS 512

typedef __bf16 bf16x8 __attribute__((ext_vector_type(8)));
typedef unsigned short u16x8 __attribute__((ext_vector_type(8)));
typedef float f32x4 __attribute__((ext_vector_type(4)));

// ws layout (bytes)
#define OFF_LRP  0u            // 256*512*4 f32 (padded xyz_)
#define OFF_BASE 2097152u      // 256*256 f32
#define OFF_W2F  2359296u      // 32768 u16  (W2 bf16 B-fragments)
#define OFF_WB   2424832u      // 2048 u16   (head [Wt|Wr|0] B-fragments)
#define WS_NEED  2428928u

__device__ __forceinline__ float fast_gelu(float x) {
    // tanh-gelu via sigmoid: x * sigmoid(2*0.79788456*(x+0.044715x^3))
    float t = x * x;
    float m = x * fmaf(t, -0.10294325f, -2.30220820f);   // -log2(e)*2u
    float e = __builtin_amdgcn_exp2f(m);
    return x * __builtin_amdgcn_rcpf(1.0f + e);
}

__device__ __forceinline__ unsigned short bf_bits(float x) {
    union { float f; unsigned u; } c; c.f = x;
    unsigned r = c.u + 0x7FFFu + ((c.u >> 16) & 1u);   // RTNE
    return (unsigned short)(r >> 16);
}

// ======================= prep kernel (257 blocks) =======================
// blocks 0..255 : centroid + LRP + base GEMV for group bx (ILP-overlapped)
// block  256    : W2 + head weight fragments (bf16, MFMA layout)
__global__ __launch_bounds__(NTHREADS, 2)
void prep_kernel(const float* __restrict__ SF, const float* __restrict__ Q,
                 const float* __restrict__ TR, const float* __restrict__ W1,
                 const float* __restrict__ b1, const float* __restrict__ W2,
                 const float* __restrict__ Wt, const float* __restrict__ Wr,
                 float* __restrict__ wsLrp, float* __restrict__ wsBase,
                 unsigned short* __restrict__ wsW2f, unsigned short* __restrict__ wsWB)
{
    const int bx = blockIdx.x;
    const int t = threadIdx.x;

    if (bx == GB) {
        // ---------- weight fragments ----------
        // W2 -> bf16 B-fragments: [(wv*8+ks)*64 + lane] * 8
        #pragma unroll 2
        for (int idx = t; idx < 4096; idx += NTHREADS) {
            int pair = idx >> 6, lane = idx & 63;
            int wv2 = pair >> 3, ks = pair & 7;
            int ln = lane & 15, lq = lane >> 4;
            int col = (wv2 << 4) | ln;
            u16x8 tmp;
            #pragma unroll
            for (int i = 0; i < 8; ++i)
                tmp[i] = bf_bits(W2[(ks * 32 + lq * 8 + i) * DH + col]);
            *(u16x8*)&wsW2f[idx * 8] = tmp;
        }
        // head [Wt|Wr|0-pad] -> bf16 B-fragments, 4 K-steps
        for (int idx = t; idx < 2048; idx += NTHREADS) {
            int ks = idx >> 9, rem = idx & 511;
            int lane = rem >> 3, i = rem & 7;
            int bq = (lane >> 4) & 3, bn = lane & 15;
            int k = ks * 32 + bq * 8 + i;
            float v = (bn < 3) ? Wt[k * 3 + bn] : (bn < 6 ? Wr[k * 3 + bn - 3] : 0.0f);
            wsWB[idx] = bf_bits(v);
        }
        return;
    }

    const int g = bx;
    __shared__ float sRed[8][4];
    __shared__ float sCent[3];
    __shared__ float sS[DD];
    __shared__ float sPart[8 * DD];   // 8 KB

    // issue all independent loads up front
    const float* trp = TR + ((size_t)g * RR + t) * 3;
    float rx = trp[0], ry = trp[1], rz = trp[2];
    const float4 q = ((const float4*)Q)[(size_t)g * RR + t];
    if (t < 64) ((float4*)sS)[t] = ((const float4*)(SF + (size_t)g * DD))[t];

    // centroid: wave shfl reduce
    float sx = rx, sy = ry, sz = rz;
    #pragma unroll
    for (int d = 1; d < 64; d <<= 1) {
        sx += __shfl_xor(sx, d); sy += __shfl_xor(sy, d); sz += __shfl_xor(sz, d);
    }
    const int wv = t >> 6, wl = t & 63;
    if (wl == 0) { sRed[wv][0] = sx; sRed[wv][1] = sy; sRed[wv][2] = sz; }
    __syncthreads();               // sS + sRed visible
    if (t == 0) {
        float cx = 0, cy = 0, cz = 0;
        #pragma unroll
        for (int i = 0; i < 8; ++i) { cx += sRed[i][0]; cy += sRed[i][1]; cz += sRed[i][2]; }
        sCent[0] = cx * (1.0f / RR); sCent[1] = cy * (1.0f / RR); sCent[2] = cz * (1.0f / RR);
    }

    // base GEMV (overlaps centroid finish): thread = (k-slice of 32, 4-col group)
    {
        const int jg = t & 63, ks = t >> 6;
        const int j4 = jg * 4, k0 = ks * 32;
        float4 acc = {0.f, 0.f, 0.f, 0.f};
        #pragma unroll 8
        for (int kk = 0; kk < 32; ++kk) {
            float s = sS[k0 + kk];
            float4 w = *(const float4*)&W1[(size_t)(k0 + kk) * DD + j4];
            acc.x = fmaf(s, w.x, acc.x);
            acc.y = fmaf(s, w.y, acc.y);
            acc.z = fmaf(s, w.z, acc.z);
            acc.w = fmaf(s, w.w, acc.w);
        }
        *(float4*)&sPart[ks * DD + j4] = acc;
    }
    __syncthreads();               // sPart + sCent visible

    if (t < DD) {
        float a = b1[t];
        #pragma unroll
        for (int i = 0; i < 8; ++i) a += sPart[i * DD + t];
        wsBase[(size_t)g * DD + t] = a;
    }

    // LRP (conjugate rotation), padded float4 — uses regs + sCent only
    {
        float ax = rx - sCent[0], ay = ry - sCent[1], az = rz - sCent[2];
        float qw = q.x, qx = q.y, qy = q.z, qz = q.w;
        float n = sqrtf(qw * qw + qx * qx + qy * qy + qz * qz) + 1e-8f;
        float inv = 1.0f / n;
        float nw = qw * inv, nx = qx * inv, ny = qy * inv, nz = qz * inv;
        float xx = nx * nx, yy = ny * ny, zz = nz * nz;
        float xy = nx * ny, xz = nx * nz, yz = ny * nz;
        float wx = nw * nx, wy = nw * ny, wz = nw * nz;
        float m00 = 1.f - 2.f * (yy + zz), m01 = 2.f * (xy - wz), m02 = 2.f * (xz + wy);
        float m10 = 2.f * (xy + wz), m11 = 1.f - 2.f * (xx + zz), m12 = 2.f * (yz - wx);
        float m20 = 2.f * (xz - wy), m21 = 2.f * (yz + wx), m22 = 1.f - 2.f * (xx + yy);
        float4 o;
        o.x = m00 * ax + m10 * ay + m20 * az;
        o.y = m01 * ax + m11 * ay + m21 * az;
        o.z = m02 * ax + m12 * ay + m22 * az;
        o.w = 0.0f;
        ((float4*)wsLrp)[(size_t)g * RR + t] = o;
    }
}

// ======================= main kernel (2048 blocks, 64 rods each) =======================
__global__ __launch_bounds__(NTHREADS, 6)
void main_kernel(const float* __restrict__ Q, const float* __restrict__ W1,
                 const float* __restrict__ b2, const float* __restrict__ bt,
                 const float* __restrict__ br,
                 const float* __restrict__ wsLrp, const float* __restrict__ wsBase,
                 const unsigned short* __restrict__ wsW2f,
                 const unsigned short* __restrict__ wsWB,
                 float* __restrict__ out)
{
    __shared__ unsigned short sH1u[64 * 264];   // 33792 B, aliased with h2 (stride 136)
    __shared__ float sDot[64][6];               // 1536 B

    const int bx = blockIdx.x;
    const int g = bx >> 3;
    const int r0 = (bx & 7) << 6;
    const int t = threadIdx.x;
    const int wv = t >> 6, wl = t & 63, ln = t & 15, lq = (t >> 4) & 3;
    const int colN = (wv << 4) | ln;
    unsigned short* sH2b = sH1u;                // alias

    // W2 B-fragments -> registers (coalesced b128 loads, L2-hot)
    bf16x8 Breg[8];
    #pragma unroll
    for (int ks = 0; ks < 8; ++ks)
        Breg[ks] = *(const bf16x8*)&wsW2f[((wv * 8 + ks) * 64 + wl) * 8];

    // per-lane phase-2 column data (4 consecutive cols per lane)
    const int l4 = wl * 4;
    const float4 base4 = *(const float4*)&wsBase[g * DD + l4];
    const float4 w1ta = *(const float4*)&W1[256 * DD + l4];
    const float4 w1tb = *(const float4*)&W1[257 * DD + l4];
    const float4 w1tc = *(const float4*)&W1[258 * DD + l4];
    const float bb = b2[colN];

    // phase 2: h1 = gelu(base + lrp.W1tail); wave wv owns rows wv*8..+8
    #pragma unroll
    for (int it = 0; it < 8; ++it) {
        int row = wv * 8 + it;
        float4 l = ((const float4*)wsLrp)[(size_t)g * RR + r0 + row];  // broadcast
        float v0 = base4.x + l.x * w1ta.x + l.y * w1tb.x + l.z * w1tc.x;
        float v1 = base4.y + l.x * w1ta.y + l.y * w1tb.y + l.z * w1tc.y;
        float v2 = base4.z + l.x * w1ta.z + l.y * w1tb.z + l.z * w1tc.z;
        float v3 = base4.w + l.x * w1ta.w + l.y * w1tb.w + l.z * w1tc.w;
        unsigned p0 = (unsigned)bf_bits(fast_gelu(v0)) | ((unsigned)bf_bits(fast_gelu(v1)) << 16);
        unsigned p1 = (unsigned)bf_bits(fast_gelu(v2)) | ((unsigned)bf_bits(fast_gelu(v3)) << 16);
        uint2 pk; pk.x = p0; pk.y = p1;
        *(uint2*)&sH1u[row * 264 + l4] = pk;
    }
    __syncthreads();

    // phase 3: MFMA h1(64x256) @ W2(256x128); wave wv -> cols [16wv, 16wv+16)
    f32x4 acc0 = {0.f, 0.f, 0.f, 0.f};
    f32x4 acc1 = {0.f, 0.f, 0.f, 0.f};
    f32x4 acc2 = {0.f, 0.f, 0.f, 0.f};
    f32x4 acc3 = {0.f, 0.f, 0.f, 0.f};
    {
        const unsigned short* aBase = sH1u + ln * 264 + lq * 8;
        #pragma unroll
        for (int ks = 0; ks < 8; ++ks) {
            bf16x8 b = Breg[ks];
            bf16x8 a0 = *(const bf16x8*)(aBase + ks * 32);
            bf16x8 a1 = *(const bf16x8*)(aBase + 16 * 264 + ks * 32);
            bf16x8 a2 = *(const bf16x8*)(aBase + 32 * 264 + ks * 32);
            bf16x8 a3 = *(const bf16x8*)(aBase + 48 * 264 + ks * 32);
            acc0 = __builtin_amdgcn_mfma_f32_16x16x32_bf16(a0, b, acc0, 0, 0, 0);
            acc1 = __builtin_amdgcn_mfma_f32_16x16x32_bf16(a1, b, acc1, 0, 0, 0);
            acc2 = __builtin_amdgcn_mfma_f32_16x16x32_bf16(a2, b, acc2, 0, 0, 0);
            acc3 = __builtin_amdgcn_mfma_f32_16x16x32_bf16(a3, b, acc3, 0, 0, 0);
        }
    }
    __syncthreads();   // all h1 reads done before aliased h2 writes

    // h2 = gelu(D + b2) -> bf16 into aliased buffer (stride 136)
    #pragma unroll
    for (int r = 0; r < 4; ++r) {
        int rq = lq * 4 + r;
        sH2b[(rq)      * 136 + colN] = bf_bits(fast_gelu(acc0[r] + bb));
        sH2b[(rq + 16) * 136 + colN] = bf_bits(fast_gelu(acc1[r] + bb));
        sH2b[(rq + 32) * 136 + colN] = bf_bits(fast_gelu(acc2[r] + bb));
        sH2b[(rq + 48) * 136 + colN] = bf_bits(fast_gelu(acc3[r] + bb));
    }
    __syncthreads();

    // head + epilogue: waves 0..3 own rows 16wv..16wv+16; no further barriers
    if (wv < 4) {
        f32x4 dacc = {0.f, 0.f, 0.f, 0.f};
        const unsigned short* aB = sH2b + (wv * 16 + ln) * 136 + lq * 8;
        #pragma unroll
        for (int ks = 0; ks < 4; ++ks) {
            bf16x8 a = *(const bf16x8*)(aB + ks * 32);
            bf16x8 b = *(const bf16x8*)(&wsWB[ks * 512 + wl * 8]);  // L2-hot global
            dacc = __builtin_amdgcn_mfma_f32_16x16x32_bf16(a, b, dacc, 0, 0, 0);
        }
        if (ln < 6) {
            #pragma unroll
            for (int r = 0; r < 4; ++r)
                sDot[wv * 16 + lq * 4 + r][ln] = dacc[r];
        }
        // wave-local ds write -> ds read: lgkmcnt handles ordering
        if (wl < 16) {
            int row = wv * 16 + wl;
            float4 q = ((const float4*)Q)[(size_t)g * RR + r0 + row];
            float qw = q.x, qx = q.y, qy = q.z, qz = q.w;
            float n = sqrtf(qw * qw + qx * qx + qy * qy + qz * qz) + 1e-8f;
            float inv = 1.0f / n;
            float nw = qw * inv, nx = qx * inv, ny = qy * inv, nz = qz * inv;
            float tvp0 = sDot[row][0] + bt[0];
            float tvp1 = sDot[row][1] + bt[1];
            float tvp2 = sDot[row][2] + bt[2];
            float rv0 = (sDot[row][3] + br[0]) * 0.1f;
            float rv1 = (sDot[row][4] + br[1]) * 0.1f;
            float rv2 = (sDot[row][5] + br[2]) * 0.1f;
            float xx = nx * nx, yy = ny * ny, zz = nz * nz;
            float xy = nx * ny, xz = nx * nz, yz = ny * nz;
            float wx = nw * nx, wy = nw * ny, wz = nw * nz;
            float m00 = 1.f - 2.f * (yy + zz), m01 = 2.f * (xy - wz), m02 = 2.f * (xz + wy);
            float m10 = 2.f * (xy + wz), m11 = 1.f - 2.f * (xx + zz), m12 = 2.f * (yz - wx);
            float m20 = 2.f * (xz - wy), m21 = 2.f * (yz + wx), m22 = 1.f - 2.f * (xx + yy);
            float tv0 = m00 * tvp0 + m01 * tvp1 + m02 * tvp2;
            float tv1 = m10 * tvp0 + m11 * tvp1 + m12 * tvp2;
            float tv2 = m20 * tvp0 + m21 * tvp1 + m22 * tvp2;
            float* op = out + ((size_t)g * RR + r0 + row) * 7;
            op[0] = -0.5f * (qx * rv0 + qy * rv1 + qz * rv2);
            op[1] =  0.5f * (qw * rv0 + qy * rv2 - qz * rv1);
            op[2] =  0.5f * (qw * rv1 - qx * rv2 + qz * rv0);
            op[3] =  0.5f * (qw * rv2 + qx * rv1 - qy * rv0);
            op[4] = tv0; op[5] = tv1; op[6] = tv2;
        }
    }
}

// ======================= fallback (single-kernel, no ws) =======================
__global__ __launch_bounds__(NTHREADS, 4)
void eq_head_fallback(const float* __restrict__ SF, const float* __restrict__ Q,
                      const float* __restrict__ TR, const float* __restrict__ W1,
                      const float* __restrict__ b1, const float* __restrict__ W2,
                      const float* __restrict__ b2, const float* __restrict__ Wt,
                      const float* __restrict__ bt, const float* __restrict__ Wr,
                      const float* __restrict__ br, float* __restrict__ out)
{
    __shared__ char sBuf[64 * 264 * 2];
    __shared__ float sLrp[RR][3];
    __shared__ float sS[DD];
    __shared__ float sW1t[3][DD];
    __shared__ float sBase[DD];
    __shared__ float sB2[DH];
    __shared__ unsigned short sWB[4 * 512];
    __shared__ float sDot[64][6];
    __shared__ float sCent[3];
    __shared__ float sBt[3];
    __shared__ float sBr[3];

    unsigned short* sH1u = (unsigned short*)sBuf;
    unsigned short* sH2b = (unsigned short*)sBuf;
    float* scratch = (float*)sBuf;

    const int g = blockIdx.x;
    const int t = threadIdx.x;
    const int wv = t >> 6, wl = t & 63, ln = t & 15, lq = (t >> 4) & 3;
    const int colN = (wv << 4) + ln;

    if (t < DD) sS[t] = SF[g * DD + t];
    for (int idx = t; idx < 3 * DD; idx += NTHREADS)
        ((float*)sW1t)[idx] = W1[DD * DD + idx];
    if (t < DH) sB2[t] = b2[t];
    if (t < 3) { sBt[t] = bt[t]; sBr[t] = br[t]; }
    for (int idx = t; idx < 2048; idx += NTHREADS) {
        int ks = idx >> 9, rem = idx & 511;
        int lane = rem >> 3, i = rem & 7;
        int bq = (lane >> 4) & 3, bn = lane & 15;
        int k = ks * 32 + bq * 8 + i;
        float v = (bn < 3) ? Wt[k * 3 + bn] : (bn < 6 ? Wr[k * 3 + bn - 3] : 0.0f);
        sWB[idx] = bf_bits(v);
    }
    {
        const float* trp = TR + ((size_t)g * RR + t) * 3;
        scratch[t] = trp[0]; scratch[512 + t] = trp[1]; scratch[1024 + t] = trp[2];
    }
    __syncthreads();
    for (int s = 256; s > 0; s >>= 1) {
        if (t < s) {
            scratch[t] += scratch[t + s];
            scratch[512 + t] += scratch[512 + t + s];
            scratch[1024 + t] += scratch[1024 + t + s];
        }
        __syncthreads();
    }
    if (t < 3) sCent[t] = scratch[t * 512] * (1.0f / RR);
    __syncthreads();
    {
        const float4 q = ((const float4*)Q)[(size_t)g * RR + t];
        const float* trp = TR + ((size_t)g * RR + t) * 3;
        float rx = trp[0] - sCent[0], ry = trp[1] - sCent[1], rz = trp[2] - sCent[2];
        float qw = q.x, qx = q.y, qy = q.z, qz = q.w;
        float n = sqrtf(qw * qw + qx * qx + qy * qy + qz * qz) + 1e-8f;
        float inv = 1.0f / n;
        float nw = qw * inv, nx = qx * inv, ny = qy * inv, nz = qz * inv;
        float xx = nx * nx, yy = ny * ny, zz = nz * nz;
        float xy = nx * ny, xz = nx * nz, yz = ny * nz;
        float wx = nw * nx, wy = nw * ny, wz = nw * nz;
        float m00 = 1.f - 2.f * (yy + zz), m01 = 2.f * (xy - wz), m02 = 2.f * (xz + wy);
        float m10 = 2.f * (xy + wz), m11 = 1.f - 2.f * (xx + zz), m12 = 2.f * (yz - wx);
        float m20 = 2.f * (xz - wy), m21 = 2.f * (yz + wx), m22 = 1.f - 2.f * (xx + yy);
        sLrp[t][0] = m00 * rx + m10 * ry + m20 * rz;
        sLrp[t][1] = m01 * rx + m11 * ry + m21 * rz;
        sLrp[t][2] = m02 * rx + m12 * ry + m22 * rz;
    }
    {
        const int j = t & 255, half = t >> 8;
        float acc0 = 0.0f;
        for (int k = half * 128; k < half * 128 + 128; ++k)
            acc0 += sS[k] * W1[k * DD + j];
        __syncthreads();
        scratch[t] = acc0;
        __syncthreads();
        if (t < DD) sBase[t] = scratch[t] + scratch[DD + t] + b1[t];
    }
    bf16x8 Breg[8];
    #pragma unroll
    for (int ks = 0; ks < 8; ++ks) {
        u16x8 tmp;
        #pragma unroll
        for (int i = 0; i < 8; ++i)
            tmp[i] = bf_bits(W2[(ks * 32 + lq * 8 + i) * DH + colN]);
        Breg[ks] = __builtin_bit_cast(bf16x8, tmp);
    }
    __syncthreads();
    const int l4 = wl * 4;
    float4 base4 = *(const float4*)&sBase[l4];
    float4 w1ta = *(const float4*)&sW1t[0][l4];
    float4 w1tb = *(const float4*)&sW1t[1][l4];
    float4 w1tc = *(const float4*)&sW1t[2][l4];
    const float4* Qv = (const float4*)Q + (size_t)g * RR;
    const int cfirst = blockIdx.y * 4;
    for (int cc = 0; cc < 4; ++cc) {
        const int r0 = (cfirst + cc) * 64;
        #pragma unroll
        for (int it = 0; it < 8; ++it) {
            int row = wv * 8 + it;
            float l0 = sLrp[r0 + row][0], l1 = sLrp[r0 + row][1], l2 = sLrp[r0 + row][2];
            float v0 = base4.x + l0 * w1ta.x + l1 * w1tb.x + l2 * w1tc.x;
            float v1 = base4.y + l0 * w1ta.y + l1 * w1tb.y + l2 * w1tc.y;
            float v2 = base4.z + l0 * w1ta.z + l1 * w1tb.z + l2 * w1tc.z;
            float v3 = base4.w + l0 * w1ta.w + l1 * w1tb.w + l2 * w1tc.w;
            unsigned p0 = (unsigned)bf_bits(fast_gelu(v0)) | ((unsigned)bf_bits(fast_gelu(v1)) << 16);
            unsigned p1 = (unsigned)bf_bits(fast_gelu(v2)) | ((unsigned)bf_bits(fast_gelu(v3)) << 16);
            uint2 pk; pk.x = p0; pk.y = p1;
            *(uint2*)&sH1u[row * 264 + l4] = pk;
        }
        __syncthreads();
        f32x4 acc0 = {0,0,0,0}, acc1 = {0,0,0,0}, acc2 = {0,0,0,0}, acc3 = {0,0,0,0};
        {
            const unsigned short* aBase = sH1u + ln * 264 + lq * 8;
            #pragma unroll
            for (int ks = 0; ks < 8; ++ks) {
                bf16x8 b = Breg[ks];
                bf16x8 a0 = *(const bf16x8*)(aBase + ks * 32);
                bf16x8 a1 = *(const bf16x8*)(aBase + 16 * 264 + ks * 32);
                bf16x8 a2 = *(const bf16x8*)(aBase + 32 * 264 + ks * 32);
                bf16x8 a3 = *(const bf16x8*)(aBase + 48 * 264 + ks * 32);
                acc0 = __builtin_amdgcn_mfma_f32_16x16x32_bf16(a0, b, acc0, 0, 0, 0);
                acc1 = __builtin_amdgcn_mfma_f32_16x16x32_bf16(a1, b, acc1, 0, 0, 0);
                acc2 = __builtin_amdgcn_mfma_f32_16x16x32_bf16(a2, b, acc2, 0, 0, 0);
                acc3 = __builtin_amdgcn_mfma_f32_16x16x32_bf16(a3, b, acc3, 0, 0, 0);
            }
        }
        __syncthreads();
        {
            float bb = sB2[colN];
            #pragma unroll
            for (int r = 0; r < 4; ++r) {
                int rq = lq * 4 + r;
                sH2b[(rq) * 136 + colN] = bf_bits(fast_gelu(acc0[r] + bb));
                sH2b[(rq + 16) * 136 + colN] = bf_bits(fast_gelu(acc1[r] + bb));
                sH2b[(rq + 32) * 136 + colN] = bf_bits(fast_gelu(acc2[r] + bb));
                sH2b[(rq + 48) * 136 + colN] = bf_bits(fast_gelu(acc3[r] + bb));
            }
        }
        __syncthreads();
        if (wv < 4) {
            f32x4 dacc = {0,0,0,0};
            const unsigned short* aB = sH2b + (wv * 16 + ln) * 136 + lq * 8;
            #pragma unroll
            for (int ks = 0; ks < 4; ++ks) {
                bf16x8 a = *(const bf16x8*)(aB + ks * 32);
                bf16x8 b = *(const bf16x8*)(&sWB[ks * 512 + wl * 8]);
                dacc = __builtin_amdgcn_mfma_f32_16x16x32_bf16(a, b, dacc, 0, 0, 0);
            }
            if (ln < 6) {
                #pragma unroll
                for (int r = 0; r < 4; ++r)
                    sDot[wv * 16 + lq * 4 + r][ln] = dacc[r];
            }
        }
        __syncthreads();
        if (t < 64) {
            float4 q = Qv[r0 + t];
            float qw = q.x, qx = q.y, qy = q.z, qz = q.w;
            float n = sqrtf(qw * qw + qx * qx + qy * qy + qz * qz) + 1e-8f;
            float inv = 1.0f / n;
            float nw = qw * inv, nx = qx * inv, ny = qy * inv, nz = qz * inv;
            float tvp0 = sDot[t][0] + sBt[0];
            float tvp1 = sDot[t][1] + sBt[1];
            float tvp2 = sDot[t][2] + sBt[2];
            float rv0 = (sDot[t][3] + sBr[0]) * 0.1f;
            float rv1 = (sDot[t][4] + sBr[1]) * 0.1f;
            float rv2 = (sDot[t][5] + sBr[2]) * 0.1f;
            float xx = nx * nx, yy = ny * ny, zz = nz * nz;
            float xy = nx * ny, xz = nx * nz, yz = ny * nz;
            float wx = nw * nx, wy = nw * ny, wz = nw * nz;
            float m00 = 1.f - 2.f * (yy + zz), m01 = 2.f * (xy - wz), m02 = 2.f * (xz + wy);
            float m10 = 2.f * (xy + wz), m11 = 1.f - 2.f * (xx + zz), m12 = 2.f * (yz - wx);
            float m20 = 2.f * (xz - wy), m21 = 2.f * (yz + wx), m22 = 1.f - 2.f * (xx + yy);
            float tv0 = m00 * tvp0 + m01 * tvp1 + m02 * tvp2;
            float tv1 = m10 * tvp0 + m11 * tvp1 + m12 * tvp2;
            float tv2 = m20 * tvp0 + m21 * tvp1 + m22 * tvp2;
            float* op = out + ((size_t)g * RR + r0 + t) * 7;
            op[0] = -0.5f * (qx * rv0 + qy * rv1 + qz * rv2);
            op[1] =  0.5f * (qw * rv0 + qy * rv2 - qz * rv1);
            op[2] =  0.5f * (qw * rv1 - qx * rv2 + qz * rv0);
            op[3] =  0.5f * (qw * rv2 + qx * rv1 - qy * rv0);
            op[4] = tv0; op[5] = tv1; op[6] = tv2;
        }
        __syncthreads();
    }
}

extern "C" void kernel_launch(void* const* d_in, const int* in_sizes, int n_in,
                              void* d_out, int out_size, void* d_ws, size_t ws_size,
                              hipStream_t stream) {
    const float* SF = (const float*)d_in[0];
    const float* Q  = (const float*)d_in[1];
    const float* TR = (const float*)d_in[2];
    const float* W1 = (const float*)d_in[3];
    const float* b1 = (const float*)d_in[4];
    const float* W2 = (const float*)d_in[5];
    const float* b2 = (const float*)d_in[6];
    const float* Wt = (const float*)d_in[7];
    const float* bt = (const float*)d_in[8];
    const float* Wr = (const float*)d_in[9];
    const float* br = (const float*)d_in[10];
    float* out = (float*)d_out;

    if (ws_size >= WS_NEED) {
        char* ws = (char*)d_ws;
        float* wsLrp = (float*)(ws + OFF_LRP);
        float* wsBase = (float*)(ws + OFF_BASE);
        unsigned short* wsW2f = (unsigned short*)(ws + OFF_W2F);
        unsigned short* wsWB = (unsigned short*)(ws + OFF_WB);
        prep_kernel<<<GB + 1, NTHREADS, 0, stream>>>(SF, Q, TR, W1, b1, W2, Wt, Wr,
                                                     wsLrp, wsBase, wsW2f, wsWB);
        main_kernel<<<GB * 8, NTHREADS, 0, stream>>>(Q, W1, b2, bt, br,
                                                     wsLrp, wsBase, wsW2f, wsWB, out);
    } else {
        dim3 grid(GB, 2);
        eq_head_fallback<<<grid, NTHREADS, 0, stream>>>(SF, Q, TR, W1, b1, W2, b2,
                                                        Wt, bt, Wr, br, out);
    }
}